// Round 4
// baseline (398.564 us; speedup 1.0000x reference)
//
#include <hip/hip_runtime.h>
#include <hip/hip_bf16.h>

#define N_    2
#define T_    7
#define C_    96
#define H_    96
#define W_    96
#define HW_   9216
#define HEAD_ 4
#define HD_   24
#define C3_   288
#define P_    12           // pixels per block: grid 1536, LDS ~49KB -> 3 blocks/CU, 24 waves/CU
#define QP_   100          // padded row stride for q/k/mid tiles (mult of 4 -> 16B-aligned)
#define CATP_ 292          // padded row stride for cat tile (mult of 4)
#define NBLK_ (N_ * (HW_ / P_))   // 1536
#define PLANES_ 14         // n*t
#define CHUNK_  64
#define NCHUNK_ 144        // 9216/64

typedef unsigned int u32;

__device__ __forceinline__ float bits2f(u32 b) {
    union { u32 u; float f; } x; x.u = b; return x.f;
}

__device__ __forceinline__ unsigned short f2bf(float f) {
    union { __hip_bfloat16 h; unsigned short s; } u;
    u.h = __float2bfloat16(f);
    return u.s;
}

template<bool BF16>
__device__ __forceinline__ float ld1(const void* p, int i) {
    if constexpr (BF16) return bits2f(((u32)((const unsigned short*)p)[i]) << 16);
    else                return ((const float*)p)[i];
}

// load 4 consecutive elements starting at i (i % 4 == 0)
template<bool BF16>
__device__ __forceinline__ void ld4w(const void* p, int i, float w[4]) {
    if constexpr (BF16) {
        const uint2 u = ((const uint2*)p)[i >> 2];
        w[0] = bits2f(u.x << 16);
        w[1] = bits2f(u.x & 0xFFFF0000u);
        w[2] = bits2f(u.y << 16);
        w[3] = bits2f(u.y & 0xFFFF0000u);
    } else {
        const float4 v = *((const float4*)((const float*)p + i));
        w[0] = v.x; w[1] = v.y; w[2] = v.z; w[3] = v.w;
    }
}

template<bool BF16>
__device__ __forceinline__ void st1(void* p, int i, float v) {
    if constexpr (BF16) ((unsigned short*)p)[i] = f2bf(v);
    else                ((float*)p)[i] = v;
}

// ---- per-block dtype detect: deterministic, same rule everywhere ----
__device__ __forceinline__ bool block_detect_bf16(const u32* __restrict__ w,
                                                  int tid, int* s_flag) {
    if (tid < 64) {
        u32 x = w[tid];
        u32 f = x & 0x7FFFu;
        int inwin = (f >= 0x3A00u) && (f <= 0x4200u);
        unsigned long long m = __ballot(inwin);
        if (tid == 0) *s_flag = (__popcll(m) >= 40) ? 1 : 0;
    }
    __syncthreads();
    return *s_flag != 0;
}

// ---- (c,hw) -> (hw,c) transpose of index_feat only, bit-exact copy ----
template<bool BF16>
__device__ __forceinline__ void transp_body(const void* __restrict__ src,
                                            void* __restrict__ dst,
                                            int bx, int tid, char* tileraw) {
    const int pl = bx / NCHUNK_;
    const int x0 = (bx - pl * NCHUNK_) * CHUNK_;
    if constexpr (BF16) {
        unsigned short (*tile)[CHUNK_ + 2] = (unsigned short (*)[CHUNK_ + 2])tileraw;
        const unsigned short* s = (const unsigned short*)src;
        unsigned short* d = (unsigned short*)dst;
        for (int i = tid; i < C_ * (CHUNK_ / 4); i += 256) {
            int ch = i >> 4, xq = i & 15;
            const ushort4 v = *((const ushort4*)(s + (pl * C_ + ch) * HW_ + x0 + 4 * xq));
            tile[ch][4 * xq + 0] = v.x; tile[ch][4 * xq + 1] = v.y;
            tile[ch][4 * xq + 2] = v.z; tile[ch][4 * xq + 3] = v.w;
        }
        __syncthreads();
        for (int i = tid; i < CHUNK_ * (C_ / 4); i += 256) {
            int p = i / 24, cq = i - p * 24;
            ushort4 v;
            v.x = tile[4 * cq + 0][p]; v.y = tile[4 * cq + 1][p];
            v.z = tile[4 * cq + 2][p]; v.w = tile[4 * cq + 3][p];
            *((ushort4*)(d + (pl * HW_ + x0 + p) * C_ + 4 * cq)) = v;
        }
    } else {
        float (*tile)[CHUNK_ + 1] = (float (*)[CHUNK_ + 1])tileraw;
        const float* s = (const float*)src;
        float* d = (float*)dst;
        for (int i = tid; i < C_ * (CHUNK_ / 4); i += 256) {
            int ch = i >> 4, xq = i & 15;
            const float4 v = *((const float4*)(s + (pl * C_ + ch) * HW_ + x0 + 4 * xq));
            tile[ch][4 * xq + 0] = v.x; tile[ch][4 * xq + 1] = v.y;
            tile[ch][4 * xq + 2] = v.z; tile[ch][4 * xq + 3] = v.w;
        }
        __syncthreads();
        for (int i = tid; i < CHUNK_ * (C_ / 4); i += 256) {
            int p = i / 24, cq = i - p * 24;
            float4 v;
            v.x = tile[4 * cq + 0][p]; v.y = tile[4 * cq + 1][p];
            v.z = tile[4 * cq + 2][p]; v.w = tile[4 * cq + 3][p];
            *((float4*)(d + (pl * HW_ + x0 + p) * C_ + 4 * cq)) = v;
        }
    }
}

__global__ __launch_bounds__(256) void transp_kernel(
    const void* __restrict__ idxf, void* __restrict__ dst,
    const u32* __restrict__ detect_src)
{
    __shared__ __align__(16) char tileraw[C_ * (CHUNK_ + 1) * 4];
    __shared__ int s_flag;
    const int tid = threadIdx.x;
    const bool bf = block_detect_bf16(detect_src, tid, &s_flag);
    if (bf) transp_body<true >(idxf, dst, blockIdx.x, tid, tileraw);
    else    transp_body<false>(idxf, dst, blockIdx.x, tid, tileraw);
}

// Frame-parallel main. MODE: 0 = scattered k-gather, 1 = k from transposed kT.
// All FP chains (norm partials j*12..+12, 8-term finish, float4 dot order,
// inv multiply, strict-> t-ascending argmax, GEMV accumulation order) are
// bit-identical to the previously verified kernels.
template<bool BF16, int MODE>
__device__ __forceinline__ void traj_body(
    const void* __restrict__ curr, const void* __restrict__ idxf,
    const void* __restrict__ anchor, const void* __restrict__ s1,
    const void* __restrict__ s2, const void* __restrict__ s3,
    const void* __restrict__ loc, const void* __restrict__ pw,
    const void* __restrict__ pb, const void* __restrict__ fw,
    const void* __restrict__ fb, void* __restrict__ outp,
    const void* __restrict__ kT,
    float* s_q, float* s_ku, float (*s_mid)[QP_], int (*s_lin)[P_],
    float* s_red, float* s_invq, float (*s_invk)[P_],
    float (*s_score)[P_][HEAD_], float (*s_best)[HEAD_], int (*s_gbase)[HEAD_])
{
#define S_Q(pp, ch)     s_q[(pp) * QP_ + (ch)]
#define S_K(t, pp, ch)  s_ku[((t) * P_ + (pp)) * QP_ + (ch)]
#define S_CAT(pp, d)    s_ku[(pp) * CATP_ + (d)]

    const int tid = threadIdx.x;
    const int b  = blockIdx.x;
    const int nn = b / (HW_ / P_);
    const int p0 = (b - nn * (HW_ / P_)) * P_;

    // ---- phase 1: nearest-sample indices (exact reference op sequence) ----
    if (tid < T_ * P_) {
        int t = tid / P_, pp = tid - t * P_;
        int p = p0 + pp;
        float x = ld1<BF16>(loc, (nn * 2 * T_ + 2 * t    ) * HW_ + p);
        float y = ld1<BF16>(loc, (nn * 2 * T_ + 2 * t + 1) * HW_ + p);
        float gx = 2.0f * x / 95.0f - 1.0f;
        float gy = 2.0f * y / 95.0f - 1.0f;
        float fx = (gx + 1.0f) * 0.5f * 95.0f;
        float fy = (gy + 1.0f) * 0.5f * 95.0f;
        float ix = rintf(fx), iy = rintf(fy);     // round-half-even == jnp.round
        bool v = (ix >= 0.0f) && (ix <= 95.0f) && (iy >= 0.0f) && (iy <= 95.0f);
        s_lin[t][pp] = v ? ((int)iy * W_ + (int)ix) : -1;
    }
    __syncthreads();

    // ---- phase 2: load curr (float4 along pixels) + gather ALL 7 k-tiles ----
    for (int i = tid; i < C_ * (P_ / 4); i += 512) {
        int ch = i / (P_ / 4), pq = i - ch * (P_ / 4);
        float w[4];
        ld4w<BF16>(curr, (nn * C_ + ch) * HW_ + p0 + 4 * pq, w);
        S_Q(4 * pq + 0, ch) = w[0]; S_Q(4 * pq + 1, ch) = w[1];
        S_Q(4 * pq + 2, ch) = w[2]; S_Q(4 * pq + 3, ch) = w[3];
    }
    if constexpr (MODE >= 1) {
        for (int i = tid; i < T_ * P_ * 24; i += 512) {
            int t = i / (P_ * 24), rem = i - t * (P_ * 24);
            int pp = rem / 24, j = rem - pp * 24;
            int lin = s_lin[t][pp];
            float w[4] = {0.f, 0.f, 0.f, 0.f};
            if (lin >= 0) ld4w<BF16>(kT, ((nn * T_ + t) * HW_ + lin) * C_ + 4 * j, w);
            *((float4*)&S_K(t, pp, 4 * j)) = make_float4(w[0], w[1], w[2], w[3]);
        }
    } else {
        for (int i = tid; i < T_ * C_ * P_; i += 512) {
            int t = i / (C_ * P_), rem = i - t * (C_ * P_);
            int ch = rem / P_, pp = rem - ch * P_;
            int lin = s_lin[t][pp];
            S_K(t, pp, ch) = (lin >= 0) ? ld1<BF16>(idxf, ((nn * T_ + t) * C_ + ch) * HW_ + lin) : 0.0f;
        }
    }
    __syncthreads();

    // ---- phase 3: q + all-frame k norm partials (same 12-elem chain) ----
    for (int i = tid; i < P_ * 8 + T_ * P_ * 8; i += 512) {
        if (i < P_ * 8) {
            int pp = i >> 3, j = i & 7;
            float s = 0.f;
            #pragma unroll
            for (int k = 0; k < 12; ++k) { float v = S_Q(pp, j * 12 + k); s += v * v; }
            s_red[pp * 8 + j] = s;
        } else {
            int idx = i - P_ * 8;
            int t = idx / (P_ * 8), rem = idx - t * (P_ * 8);
            int pp = rem >> 3, j = rem & 7;
            float s = 0.f;
            #pragma unroll
            for (int k = 0; k < 12; ++k) { float v = S_K(t, pp, j * 12 + k); s += v * v; }
            s_red[P_ * 8 + (t * P_ + pp) * 8 + j] = s;
        }
    }
    __syncthreads();

    // ---- phase 4: norm finish (same 8-term order) ----
    if (tid < P_ + T_ * P_) {
        if (tid < P_) {
            float s = 0.f;
            #pragma unroll
            for (int j = 0; j < 8; ++j) s += s_red[tid * 8 + j];
            s_invq[tid] = 1.0f / fmaxf(sqrtf(s), 1e-12f);
        } else {
            int idx = tid - P_;
            int t = idx / P_, pp = idx - t * P_;
            float s = 0.f;
            #pragma unroll
            for (int j = 0; j < 8; ++j) s += s_red[P_ * 8 + (t * P_ + pp) * 8 + j];
            s_invk[t][pp] = 1.0f / fmaxf(sqrtf(s), 1e-12f);
        }
    }
    __syncthreads();

    // ---- phase 5: scale q in place (same per-element multiply) ----
    for (int i = tid; i < P_ * 24; i += 512) {
        int pp = i / 24, chq = i - pp * 24;
        float4* p4 = (float4*)&S_Q(pp, 4 * chq);
        float4 v = *p4;
        float iv = s_invq[pp];
        v.x *= iv; v.y *= iv; v.z *= iv; v.w *= iv;
        *p4 = v;
    }
    __syncthreads();

    // ---- phase 6: all 336 dots in parallel (same float4 chain + inv mult) ----
    for (int i = tid; i < T_ * P_ * HEAD_; i += 512) {
        int t = i / (P_ * HEAD_), rem = i - t * (P_ * HEAD_);
        int pp = rem >> 2, h = rem & 3;
        float s = 0.f;
        #pragma unroll
        for (int dq = 0; dq < 6; ++dq) {
            const float4 kv = *((const float4*)&S_K(t, pp, h * HD_ + 4 * dq));
            const float4 qv = *((const float4*)&S_Q(pp, h * HD_ + 4 * dq));
            s += kv.x * qv.x; s += kv.y * qv.y; s += kv.z * qv.z; s += kv.w * qv.w;
        }
        s *= s_invk[t][pp];
        s_score[t][pp][h] = s;
    }
    __syncthreads();

    // ---- phase 7: ordered argmax scan (t ascending, strict > == first-max) ----
    if (tid < P_ * HEAD_) {
        int pp = tid >> 2, h = tid & 3;
        float best = -3.0e38f; int bidx = 0;
        #pragma unroll
        for (int t = 0; t < T_; ++t) {
            float v = s_score[t][pp][h];
            if (v > best) { best = v; bidx = t; }
        }
        s_best[pp][h] = best;
        int lin = s_lin[bidx][pp];
        s_gbase[pp][h] = (lin >= 0) ? ((nn * T_ + bidx) * C_ * HW_ + lin) : -1;
    }
    __syncthreads();

    // ---- phase 8: scattered cat gather (precomputed bases; overlays k) ----
    for (int i = tid; i < C3_ * P_; i += 512) {
        int pp = i / C3_, d = i - pp * C3_;
        int set = d / C_, ch = d - set * C_;
        int gb = s_gbase[pp][ch / HD_];
        float v = 0.f;
        if (gb >= 0) {
            const void* sp = (set == 0) ? s1 : (set == 1) ? s2 : s3;
            v = ld1<BF16>(sp, gb + ch * HW_);
        }
        S_CAT(pp, d) = v;
    }
    __syncthreads();

    // ---- phase 9: fusion GEMV (96 x 288), thread = (co-quad, pixel) ----
    // pixel in low lane bits -> fw loads are wave-broadcast (one address/group)
    if (tid < 24 * P_) {
        const int cq = tid / P_, px = tid - cq * P_;
        const int co0 = cq * 4;
        float acc[4] = {0.f, 0.f, 0.f, 0.f};
        for (int d = 0; d < C3_; d += 4) {
            const float4 cv = *((const float4*)&S_CAT(px, d));
            #pragma unroll
            for (int r = 0; r < 4; ++r) {
                float w[4]; ld4w<BF16>(fw, (co0 + r) * C3_ + d, w);
                acc[r] += w[0] * cv.x + w[1] * cv.y + w[2] * cv.z + w[3] * cv.w;
            }
        }
        const int hh = co0 / HD_;   // 4 co's never straddle a head
        float soft = s_best[px][hh];
        #pragma unroll
        for (int r = 0; r < 4; ++r)
            s_mid[px][co0 + r] = (acc[r] + ld1<BF16>(fb, co0 + r)) * soft;
    }
    __syncthreads();

    // ---- phase 10: proj GEMV (96 x 96) + bias + anchor, store ----
    if (tid < 24 * P_) {
        const int dq = tid / P_, px = tid - dq * P_;
        const int do0 = dq * 4;
        float acc[4] = {0.f, 0.f, 0.f, 0.f};
        for (int c = 0; c < C_; c += 4) {
            const float4 mv = *((const float4*)&s_mid[px][c]);
            #pragma unroll
            for (int r = 0; r < 4; ++r) {
                float w[4]; ld4w<BF16>(pw, (do0 + r) * C_ + c, w);
                acc[r] += w[0] * mv.x + w[1] * mv.y + w[2] * mv.z + w[3] * mv.w;
            }
        }
        int p = p0 + px;
        #pragma unroll
        for (int r = 0; r < 4; ++r) {
            float res = acc[r] + ld1<BF16>(pb, do0 + r)
                      + ld1<BF16>(anchor, (nn * C_ + do0 + r) * HW_ + p);
            st1<BF16>(outp, (nn * C_ + do0 + r) * HW_ + p, res);
        }
    }
#undef S_Q
#undef S_K
#undef S_CAT
}

template<int MODE>
__global__ __launch_bounds__(512, 6) void traj_main(
    const void* __restrict__ curr, const void* __restrict__ idxf,
    const void* __restrict__ anchor, const void* __restrict__ s1,
    const void* __restrict__ s2, const void* __restrict__ s3,
    const void* __restrict__ loc, const void* __restrict__ pw,
    const void* __restrict__ pb, const void* __restrict__ fw,
    const void* __restrict__ fb, void* __restrict__ outp,
    const void* __restrict__ kT)
{
    __shared__ __align__(16) float s_q[P_ * QP_];            // 4.8 KB
    __shared__ __align__(16) float s_ku[T_ * P_ * QP_];      // 33.6 KB; cat (P_*CATP_=3504f) overlays
    __shared__ __align__(16) float s_mid[P_][QP_];           // 4.8 KB
    __shared__ int   s_lin[T_][P_];
    __shared__ float s_red[P_ * 8 + T_ * P_ * 8];
    __shared__ float s_invq[P_];
    __shared__ float s_invk[T_][P_];
    __shared__ float s_score[T_][P_][HEAD_];
    __shared__ float s_best[P_][HEAD_];
    __shared__ int   s_gbase[P_][HEAD_];
    __shared__ int   s_flag;

    const bool bf = block_detect_bf16((const u32*)curr, threadIdx.x, &s_flag);
    if (bf) traj_body<true,  MODE>(curr, idxf, anchor, s1, s2, s3, loc, pw, pb, fw, fb,
                                   outp, kT, s_q, s_ku, s_mid, s_lin, s_red,
                                   s_invq, s_invk, s_score, s_best, s_gbase);
    else    traj_body<false, MODE>(curr, idxf, anchor, s1, s2, s3, loc, pw, pb, fw, fb,
                                   outp, kT, s_q, s_ku, s_mid, s_lin, s_red,
                                   s_invq, s_invk, s_score, s_best, s_gbase);
}

extern "C" void kernel_launch(void* const* d_in, const int* in_sizes, int n_in,
                              void* d_out, int out_size, void* d_ws, size_t ws_size,
                              hipStream_t stream) {
    (void)in_sizes; (void)n_in; (void)out_size;
    const unsigned long long SZB = (unsigned long long)N_ * T_ * HW_ * C_ * 4ull; // 49.5 MB (f32 worst case)
    void* kT = d_ws;
    const int mode = (ws_size >= SZB) ? 1 : 0;

    dim3 grid(NBLK_), block(512);
    if (mode == 1) {
        transp_kernel<<<dim3(PLANES_ * NCHUNK_), 256, 0, stream>>>(d_in[1], kT, (const u32*)d_in[0]);
        traj_main<1><<<grid, block, 0, stream>>>(d_in[0], d_in[1], d_in[2], d_in[3], d_in[4],
                                                 d_in[5], d_in[6], d_in[7], d_in[8], d_in[9],
                                                 d_in[10], d_out, kT);
    } else {
        traj_main<0><<<grid, block, 0, stream>>>(d_in[0], d_in[1], d_in[2], d_in[3], d_in[4],
                                                 d_in[5], d_in[6], d_in[7], d_in[8], d_in[9],
                                                 d_in[10], d_out, kT);
    }
}

// Round 5
// 381.245 us; speedup vs baseline: 1.0454x; 1.0454x over previous
//
#include <hip/hip_runtime.h>
#include <hip/hip_bf16.h>

#define N_    2
#define T_    7
#define C_    96
#define H_    96
#define W_    96
#define HW_   9216
#define HEAD_ 4
#define HD_   24
#define C3_   288
#define P_    16           // pixels per block: grid 1152, 256 threads, full-line output stores
#define QP_   100          // padded row stride for q/k tiles (mult of 4 -> 16B-aligned)
#define CATP_ 292          // padded row stride for cat tile (mult of 4)
#define NBLK_ (N_ * (HW_ / P_))   // 1152
#define PLANES_ 14         // n*t
#define CHUNK_  64
#define NCHUNK_ 144        // 9216/64

typedef unsigned int u32;

__device__ __forceinline__ float bits2f(u32 b) {
    union { u32 u; float f; } x; x.u = b; return x.f;
}

__device__ __forceinline__ unsigned short f2bf(float f) {
    union { __hip_bfloat16 h; unsigned short s; } u;
    u.h = __float2bfloat16(f);
    return u.s;
}

template<bool BF16>
__device__ __forceinline__ float ld1(const void* p, int i) {
    if constexpr (BF16) return bits2f(((u32)((const unsigned short*)p)[i]) << 16);
    else                return ((const float*)p)[i];
}

// load 4 consecutive elements starting at i (i % 4 == 0)
template<bool BF16>
__device__ __forceinline__ void ld4w(const void* p, int i, float w[4]) {
    if constexpr (BF16) {
        const uint2 u = ((const uint2*)p)[i >> 2];
        w[0] = bits2f(u.x << 16);
        w[1] = bits2f(u.x & 0xFFFF0000u);
        w[2] = bits2f(u.y << 16);
        w[3] = bits2f(u.y & 0xFFFF0000u);
    } else {
        const float4 v = *((const float4*)((const float*)p + i));
        w[0] = v.x; w[1] = v.y; w[2] = v.z; w[3] = v.w;
    }
}

template<bool BF16>
__device__ __forceinline__ void st1(void* p, int i, float v) {
    if constexpr (BF16) ((unsigned short*)p)[i] = f2bf(v);
    else                ((float*)p)[i] = v;
}

// ---- per-block dtype detect: deterministic, same rule everywhere ----
__device__ __forceinline__ bool block_detect_bf16(const u32* __restrict__ w,
                                                  int tid, int* s_flag) {
    if (tid < 64) {
        u32 x = w[tid];
        u32 f = x & 0x7FFFu;
        int inwin = (f >= 0x3A00u) && (f <= 0x4200u);
        unsigned long long m = __ballot(inwin);
        if (tid == 0) *s_flag = (__popcll(m) >= 40) ? 1 : 0;
    }
    __syncthreads();
    return *s_flag != 0;
}

// ---- (c,hw) -> (hw,c) transpose of index_feat only, bit-exact copy ----
template<bool BF16>
__device__ __forceinline__ void transp_body(const void* __restrict__ src,
                                            void* __restrict__ dst,
                                            int bx, int tid, char* tileraw) {
    const int pl = bx / NCHUNK_;
    const int x0 = (bx - pl * NCHUNK_) * CHUNK_;
    if constexpr (BF16) {
        unsigned short (*tile)[CHUNK_ + 2] = (unsigned short (*)[CHUNK_ + 2])tileraw;
        const unsigned short* s = (const unsigned short*)src;
        unsigned short* d = (unsigned short*)dst;
        for (int i = tid; i < C_ * (CHUNK_ / 4); i += 256) {
            int ch = i >> 4, xq = i & 15;
            const ushort4 v = *((const ushort4*)(s + (pl * C_ + ch) * HW_ + x0 + 4 * xq));
            tile[ch][4 * xq + 0] = v.x; tile[ch][4 * xq + 1] = v.y;
            tile[ch][4 * xq + 2] = v.z; tile[ch][4 * xq + 3] = v.w;
        }
        __syncthreads();
        for (int i = tid; i < CHUNK_ * (C_ / 4); i += 256) {
            int p = i / 24, cq = i - p * 24;
            ushort4 v;
            v.x = tile[4 * cq + 0][p]; v.y = tile[4 * cq + 1][p];
            v.z = tile[4 * cq + 2][p]; v.w = tile[4 * cq + 3][p];
            *((ushort4*)(d + (pl * HW_ + x0 + p) * C_ + 4 * cq)) = v;
        }
    } else {
        float (*tile)[CHUNK_ + 1] = (float (*)[CHUNK_ + 1])tileraw;
        const float* s = (const float*)src;
        float* d = (float*)dst;
        for (int i = tid; i < C_ * (CHUNK_ / 4); i += 256) {
            int ch = i >> 4, xq = i & 15;
            const float4 v = *((const float4*)(s + (pl * C_ + ch) * HW_ + x0 + 4 * xq));
            tile[ch][4 * xq + 0] = v.x; tile[ch][4 * xq + 1] = v.y;
            tile[ch][4 * xq + 2] = v.z; tile[ch][4 * xq + 3] = v.w;
        }
        __syncthreads();
        for (int i = tid; i < CHUNK_ * (C_ / 4); i += 256) {
            int p = i / 24, cq = i - p * 24;
            float4 v;
            v.x = tile[4 * cq + 0][p]; v.y = tile[4 * cq + 1][p];
            v.z = tile[4 * cq + 2][p]; v.w = tile[4 * cq + 3][p];
            *((float4*)(d + (pl * HW_ + x0 + p) * C_ + 4 * cq)) = v;
        }
    }
}

__global__ __launch_bounds__(256) void transp_kernel(
    const void* __restrict__ idxf, void* __restrict__ dst,
    const u32* __restrict__ detect_src)
{
    __shared__ __align__(16) char tileraw[C_ * (CHUNK_ + 1) * 4];
    __shared__ int s_flag;
    const int tid = threadIdx.x;
    const bool bf = block_detect_bf16(detect_src, tid, &s_flag);
    if (bf) transp_body<true >(idxf, dst, blockIdx.x, tid, tileraw);
    else    transp_body<false>(idxf, dst, blockIdx.x, tid, tileraw);
}

// Round-2 structure (P=16, 256 threads) + 2-frame unroll + register argmax
// + flat GEMVs. All FP chains (12-elem norm partials, 8-term finish, float4
// dot order, inv multiply, strict-> t-ascending argmax, d-ascending GEMV
// accumulation grouping) bit-identical to the verified kernels.
template<bool BF16, int MODE>
__device__ __forceinline__ void traj_body(
    const void* __restrict__ curr, const void* __restrict__ idxf,
    const void* __restrict__ anchor, const void* __restrict__ s1,
    const void* __restrict__ s2, const void* __restrict__ s3,
    const void* __restrict__ loc, const void* __restrict__ pw,
    const void* __restrict__ pb, const void* __restrict__ fw,
    const void* __restrict__ fb, void* __restrict__ outp,
    const void* __restrict__ kT,
    float* s_u, float (*s_mid)[QP_], int (*s_lin)[P_],
    float (*s_red)[P_][8], float* s_invq, float (*s_invk)[P_],
    float (*s_best)[HEAD_], int (*s_gbase)[HEAD_])
{
#define S_Q(pp, ch)      s_u[(pp) * QP_ + (ch)]
#define S_KF(f, pp, ch)  s_u[P_ * QP_ + (f) * (P_ * QP_) + (pp) * QP_ + (ch)]
#define S_CAT(pp, d)     s_u[(pp) * CATP_ + (d)]

    const int tid = threadIdx.x;
    const int b  = blockIdx.x;
    const int nn = b / (HW_ / P_);
    const int p0 = (b - nn * (HW_ / P_)) * P_;

    // ---- nearest-sample indices (exact reference op sequence) ----
    if (tid < T_ * P_) {
        int t = tid / P_, pp = tid - t * P_;
        int p = p0 + pp;
        float x = ld1<BF16>(loc, (nn * 2 * T_ + 2 * t    ) * HW_ + p);
        float y = ld1<BF16>(loc, (nn * 2 * T_ + 2 * t + 1) * HW_ + p);
        float gx = 2.0f * x / 95.0f - 1.0f;
        float gy = 2.0f * y / 95.0f - 1.0f;
        float fx = (gx + 1.0f) * 0.5f * 95.0f;
        float fy = (gy + 1.0f) * 0.5f * 95.0f;
        float ix = rintf(fx), iy = rintf(fy);     // round-half-even == jnp.round
        bool v = (ix >= 0.0f) && (ix <= 95.0f) && (iy >= 0.0f) && (iy <= 95.0f);
        s_lin[t][pp] = v ? ((int)iy * W_ + (int)ix) : -1;
    }

    // ---- load curr (float4 along pixels, coalesced) ----
    for (int i = tid; i < C_ * (P_ / 4); i += 256) {
        int ch = i >> 2, pq = i & 3;
        float w[4];
        ld4w<BF16>(curr, (nn * C_ + ch) * HW_ + p0 + 4 * pq, w);
        S_Q(4 * pq + 0, ch) = w[0]; S_Q(4 * pq + 1, ch) = w[1];
        S_Q(4 * pq + 2, ch) = w[2]; S_Q(4 * pq + 3, ch) = w[3];
    }
    __syncthreads();

    // ---- q L2 norm over full c (before head split) ----
    if (tid < P_ * 8) {
        int pp = tid >> 3, j = tid & 7;
        float s = 0.f;
        #pragma unroll
        for (int k = 0; k < 12; ++k) { float v = S_Q(pp, j * 12 + k); s += v * v; }
        s_red[0][pp][j] = s;
    }
    __syncthreads();
    if (tid < P_) {
        float s = 0.f;
        #pragma unroll
        for (int j = 0; j < 8; ++j) s += s_red[0][tid][j];
        s_invq[tid] = 1.0f / fmaxf(sqrtf(s), 1e-12f);
    }
    __syncthreads();
    for (int i = tid; i < C_ * P_; i += 256) {
        int pp = i & (P_ - 1), ch = i >> 4;
        S_Q(pp, ch) *= s_invq[pp];
    }

    // ---- frame loop, 2-frame unrolled; argmax state lives in registers of
    //      the owning (pp,h) thread (tid < 64, stable across iterations) ----
    float best = -3.0e38f; int bidx = 0;
    const int dpp = tid >> 2, dh = tid & 3;

    for (int tp = 0; tp < 3; ++tp) {
        const int tA = 2 * tp;
        __syncthreads();   // k buffers free (prev dot readers done; iter 0: q-scale done)
        if constexpr (MODE >= 1) {
            for (int i = tid; i < 2 * 24 * P_; i += 256) {
                int f = i / (24 * P_), rem = i - f * (24 * P_);
                int pp = rem / 24, j = rem - pp * 24;
                int lin = s_lin[tA + f][pp];
                float w[4] = {0.f, 0.f, 0.f, 0.f};
                if (lin >= 0) ld4w<BF16>(kT, ((nn * T_ + tA + f) * HW_ + lin) * C_ + 4 * j, w);
                *((float4*)&S_KF(f, pp, 4 * j)) = make_float4(w[0], w[1], w[2], w[3]);
            }
        } else {
            for (int i = tid; i < 2 * C_ * P_; i += 256) {
                int f = i / (C_ * P_), rem = i - f * (C_ * P_);
                int ch = rem / P_, pp = rem - ch * P_;
                int lin = s_lin[tA + f][pp];
                S_KF(f, pp, ch) = (lin >= 0)
                    ? ld1<BF16>(idxf, ((nn * T_ + tA + f) * C_ + ch) * HW_ + lin) : 0.0f;
            }
        }
        __syncthreads();
        {   // norm partials: all 256 threads, 2 frames (same 12-elem chain)
            int f = tid >> 7, rem = tid & 127;
            int pp = rem >> 3, j = rem & 7;
            float s = 0.f;
            #pragma unroll
            for (int k = 0; k < 12; ++k) { float v = S_KF(f, pp, j * 12 + k); s += v * v; }
            s_red[f][pp][j] = s;
        }
        __syncthreads();
        if (tid < 2 * P_) {   // norm finish (same 8-term order)
            int f = tid >> 4, pp = tid & 15;
            float s = 0.f;
            #pragma unroll
            for (int j = 0; j < 8; ++j) s += s_red[f][pp][j];
            s_invk[f][pp] = 1.0f / fmaxf(sqrtf(s), 1e-12f);
        }
        __syncthreads();
        if (tid < P_ * HEAD_) {   // dots, frame A then B (ascending t, strict >)
            #pragma unroll
            for (int f = 0; f < 2; ++f) {
                float s = 0.f;
                #pragma unroll
                for (int dq = 0; dq < 6; ++dq) {
                    const float4 kv = *((const float4*)&S_KF(f, dpp, dh * HD_ + 4 * dq));
                    const float4 qv = *((const float4*)&S_Q(dpp, dh * HD_ + 4 * dq));
                    s += kv.x * qv.x; s += kv.y * qv.y; s += kv.z * qv.z; s += kv.w * qv.w;
                }
                s *= s_invk[f][dpp];
                if (s > best) { best = s; bidx = tA + f; }
            }
        }
    }
    // ---- tail frame t = 6 ----
    __syncthreads();
    if constexpr (MODE >= 1) {
        for (int i = tid; i < 24 * P_; i += 256) {
            int pp = i / 24, j = i - pp * 24;
            int lin = s_lin[6][pp];
            float w[4] = {0.f, 0.f, 0.f, 0.f};
            if (lin >= 0) ld4w<BF16>(kT, ((nn * T_ + 6) * HW_ + lin) * C_ + 4 * j, w);
            *((float4*)&S_KF(0, pp, 4 * j)) = make_float4(w[0], w[1], w[2], w[3]);
        }
    } else {
        for (int i = tid; i < C_ * P_; i += 256) {
            int ch = i / P_, pp = i - ch * P_;
            int lin = s_lin[6][pp];
            S_KF(0, pp, ch) = (lin >= 0)
                ? ld1<BF16>(idxf, ((nn * T_ + 6) * C_ + ch) * HW_ + lin) : 0.0f;
        }
    }
    __syncthreads();
    if (tid < P_ * 8) {
        int pp = tid >> 3, j = tid & 7;
        float s = 0.f;
        #pragma unroll
        for (int k = 0; k < 12; ++k) { float v = S_KF(0, pp, j * 12 + k); s += v * v; }
        s_red[0][pp][j] = s;
    }
    __syncthreads();
    if (tid < P_) {
        float s = 0.f;
        #pragma unroll
        for (int j = 0; j < 8; ++j) s += s_red[0][tid][j];
        s_invk[0][tid] = 1.0f / fmaxf(sqrtf(s), 1e-12f);
    }
    __syncthreads();
    if (tid < P_ * HEAD_) {
        float s = 0.f;
        #pragma unroll
        for (int dq = 0; dq < 6; ++dq) {
            const float4 kv = *((const float4*)&S_KF(0, dpp, dh * HD_ + 4 * dq));
            const float4 qv = *((const float4*)&S_Q(dpp, dh * HD_ + 4 * dq));
            s += kv.x * qv.x; s += kv.y * qv.y; s += kv.z * qv.z; s += kv.w * qv.w;
        }
        s *= s_invk[0][dpp];
        if (s > best) { best = s; bidx = 6; }
        s_best[dpp][dh] = best;
        int lin = s_lin[bidx][dpp];
        s_gbase[dpp][dh] = (lin >= 0) ? ((nn * T_ + bidx) * C_ * HW_ + lin) : -1;
    }
    __syncthreads();

    // ---- scattered cat gather (precomputed bases; overlays q/k region) ----
    for (int i = tid; i < C3_ * P_; i += 256) {
        int pp = i / C3_, d = i - pp * C3_;
        int set = d / C_, ch = d - set * C_;
        int gb = s_gbase[pp][ch / HD_];
        float v = 0.f;
        if (gb >= 0) {
            const void* sp = (set == 0) ? s1 : (set == 1) ? s2 : s3;
            v = ld1<BF16>(sp, gb + ch * HW_);
        }
        S_CAT(pp, d) = v;
    }
    __syncthreads();

    // ---- fusion GEMV (96 x 288): flat (co, px), px in lane-low-bits so
    //      fw row loads are 16-lane broadcast; same d-ascending FP chain ----
    for (int u = tid; u < C_ * P_; u += 256) {
        int co = u >> 4, px = u & 15;
        float acc = 0.f;
        for (int d = 0; d < C3_; d += 4) {
            float w[4]; ld4w<BF16>(fw, co * C3_ + d, w);
            const float4 cv = *((const float4*)&S_CAT(px, d));
            acc += w[0] * cv.x + w[1] * cv.y + w[2] * cv.z + w[3] * cv.w;
        }
        s_mid[px][co] = (acc + ld1<BF16>(fb, co)) * s_best[px][co / HD_];
    }
    __syncthreads();

    // ---- proj GEMV (96 x 96) + bias + anchor; full-line coalesced stores ----
    for (int u = tid; u < C_ * P_; u += 256) {
        int dd = u >> 4, px = u & 15;
        float acc = 0.f;
        for (int c = 0; c < C_; c += 4) {
            float w[4]; ld4w<BF16>(pw, dd * C_ + c, w);
            const float4 mv = *((const float4*)&s_mid[px][c]);
            acc += w[0] * mv.x + w[1] * mv.y + w[2] * mv.z + w[3] * mv.w;
        }
        int p = p0 + px;
        float res = acc + ld1<BF16>(pb, dd)
                  + ld1<BF16>(anchor, (nn * C_ + dd) * HW_ + p);
        st1<BF16>(outp, (nn * C_ + dd) * HW_ + p, res);
    }
#undef S_Q
#undef S_KF
#undef S_CAT
}

template<int MODE>
__global__ __launch_bounds__(256) void traj_main(
    const void* __restrict__ curr, const void* __restrict__ idxf,
    const void* __restrict__ anchor, const void* __restrict__ s1,
    const void* __restrict__ s2, const void* __restrict__ s3,
    const void* __restrict__ loc, const void* __restrict__ pw,
    const void* __restrict__ pb, const void* __restrict__ fw,
    const void* __restrict__ fb, void* __restrict__ outp,
    const void* __restrict__ kT)
{
    __shared__ __align__(16) float s_u[3 * P_ * QP_];   // q | kA | kB (4800 fl); cat (4672) overlays
    __shared__ __align__(16) float s_mid[P_][QP_];
    __shared__ int   s_lin[T_][P_];
    __shared__ float s_red[2][P_][8];
    __shared__ float s_invq[P_];
    __shared__ float s_invk[2][P_];
    __shared__ float s_best[P_][HEAD_];
    __shared__ int   s_gbase[P_][HEAD_];
    __shared__ int   s_flag;

    const bool bf = block_detect_bf16((const u32*)curr, threadIdx.x, &s_flag);
    if (bf) traj_body<true,  MODE>(curr, idxf, anchor, s1, s2, s3, loc, pw, pb, fw, fb,
                                   outp, kT, s_u, s_mid, s_lin, s_red, s_invq,
                                   s_invk, s_best, s_gbase);
    else    traj_body<false, MODE>(curr, idxf, anchor, s1, s2, s3, loc, pw, pb, fw, fb,
                                   outp, kT, s_u, s_mid, s_lin, s_red, s_invq,
                                   s_invk, s_best, s_gbase);
}

extern "C" void kernel_launch(void* const* d_in, const int* in_sizes, int n_in,
                              void* d_out, int out_size, void* d_ws, size_t ws_size,
                              hipStream_t stream) {
    (void)in_sizes; (void)n_in; (void)out_size;
    const unsigned long long SZB = (unsigned long long)N_ * T_ * HW_ * C_ * 4ull; // 49.5 MB (f32 worst case)
    void* kT = d_ws;
    const int mode = (ws_size >= SZB) ? 1 : 0;

    dim3 grid(NBLK_), block(256);
    if (mode == 1) {
        transp_kernel<<<dim3(PLANES_ * NCHUNK_), 256, 0, stream>>>(d_in[1], kT, (const u32*)d_in[0]);
        traj_main<1><<<grid, block, 0, stream>>>(d_in[0], d_in[1], d_in[2], d_in[3], d_in[4],
                                                 d_in[5], d_in[6], d_in[7], d_in[8], d_in[9],
                                                 d_in[10], d_out, kT);
    } else {
        traj_main<0><<<grid, block, 0, stream>>>(d_in[0], d_in[1], d_in[2], d_in[3], d_in[4],
                                                 d_in[5], d_in[6], d_in[7], d_in[8], d_in[9],
                                                 d_in[10], d_out, kT);
    }
}

// Round 6
// 323.644 us; speedup vs baseline: 1.2315x; 1.1780x over previous
//
#include <hip/hip_runtime.h>
#include <hip/hip_bf16.h>

#define N_    2
#define T_    7
#define C_    96
#define H_    96
#define W_    96
#define HW_   9216
#define HEAD_ 4
#define HD_   24
#define C3_   288
#define P_    16           // pixels per block: grid 1152, 256 threads, full-line output stores
#define QP_   100          // padded row stride for q/k tiles (mult of 4 -> 16B-aligned)
#define CATP_ 292          // padded row stride for cat tile (mult of 4)
#define NBLK_ (N_ * (HW_ / P_))   // 1152
#define PLANES_ 14         // n*t
#define CHUNK_  64
#define NCHUNK_ 144        // 9216/64

typedef unsigned int u32;

__device__ __forceinline__ float bits2f(u32 b) {
    union { u32 u; float f; } x; x.u = b; return x.f;
}

__device__ __forceinline__ unsigned short f2bf(float f) {
    union { __hip_bfloat16 h; unsigned short s; } u;
    u.h = __float2bfloat16(f);
    return u.s;
}

template<bool BF16>
__device__ __forceinline__ float ld1(const void* p, int i) {
    if constexpr (BF16) return bits2f(((u32)((const unsigned short*)p)[i]) << 16);
    else                return ((const float*)p)[i];
}

// load 4 consecutive elements starting at i (i % 4 == 0)
template<bool BF16>
__device__ __forceinline__ void ld4w(const void* p, int i, float w[4]) {
    if constexpr (BF16) {
        const uint2 u = ((const uint2*)p)[i >> 2];
        w[0] = bits2f(u.x << 16);
        w[1] = bits2f(u.x & 0xFFFF0000u);
        w[2] = bits2f(u.y << 16);
        w[3] = bits2f(u.y & 0xFFFF0000u);
    } else {
        const float4 v = *((const float4*)((const float*)p + i));
        w[0] = v.x; w[1] = v.y; w[2] = v.z; w[3] = v.w;
    }
}

template<bool BF16>
__device__ __forceinline__ void st1(void* p, int i, float v) {
    if constexpr (BF16) ((unsigned short*)p)[i] = f2bf(v);
    else                ((float*)p)[i] = v;
}

// store 4 consecutive elements starting at i (i % 4 == 0)
template<bool BF16>
__device__ __forceinline__ void st4w(void* p, int i, const float v[4]) {
    if constexpr (BF16) {
        uint2 w;
        w.x = (u32)f2bf(v[0]) | ((u32)f2bf(v[1]) << 16);
        w.y = (u32)f2bf(v[2]) | ((u32)f2bf(v[3]) << 16);
        ((uint2*)p)[i >> 2] = w;
    } else {
        *((float4*)((float*)p + i)) = make_float4(v[0], v[1], v[2], v[3]);
    }
}

// ---- per-block dtype detect: deterministic, same rule everywhere ----
__device__ __forceinline__ bool block_detect_bf16(const u32* __restrict__ w,
                                                  int tid, int* s_flag) {
    if (tid < 64) {
        u32 x = w[tid];
        u32 f = x & 0x7FFFu;
        int inwin = (f >= 0x3A00u) && (f <= 0x4200u);
        unsigned long long m = __ballot(inwin);
        if (tid == 0) *s_flag = (__popcll(m) >= 40) ? 1 : 0;
    }
    __syncthreads();
    return *s_flag != 0;
}

// ---- (c,hw) -> (hw,c) transpose of index_feat only, bit-exact copy ----
template<bool BF16>
__device__ __forceinline__ void transp_body(const void* __restrict__ src,
                                            void* __restrict__ dst,
                                            int bx, int tid, char* tileraw) {
    const int pl = bx / NCHUNK_;
    const int x0 = (bx - pl * NCHUNK_) * CHUNK_;
    if constexpr (BF16) {
        unsigned short (*tile)[CHUNK_ + 2] = (unsigned short (*)[CHUNK_ + 2])tileraw;
        const unsigned short* s = (const unsigned short*)src;
        unsigned short* d = (unsigned short*)dst;
        for (int i = tid; i < C_ * (CHUNK_ / 4); i += 256) {
            int ch = i >> 4, xq = i & 15;
            const ushort4 v = *((const ushort4*)(s + (pl * C_ + ch) * HW_ + x0 + 4 * xq));
            tile[ch][4 * xq + 0] = v.x; tile[ch][4 * xq + 1] = v.y;
            tile[ch][4 * xq + 2] = v.z; tile[ch][4 * xq + 3] = v.w;
        }
        __syncthreads();
        for (int i = tid; i < CHUNK_ * (C_ / 4); i += 256) {
            int p = i / 24, cq = i - p * 24;
            ushort4 v;
            v.x = tile[4 * cq + 0][p]; v.y = tile[4 * cq + 1][p];
            v.z = tile[4 * cq + 2][p]; v.w = tile[4 * cq + 3][p];
            *((ushort4*)(d + (pl * HW_ + x0 + p) * C_ + 4 * cq)) = v;
        }
    } else {
        float (*tile)[CHUNK_ + 1] = (float (*)[CHUNK_ + 1])tileraw;
        const float* s = (const float*)src;
        float* d = (float*)dst;
        for (int i = tid; i < C_ * (CHUNK_ / 4); i += 256) {
            int ch = i >> 4, xq = i & 15;
            const float4 v = *((const float4*)(s + (pl * C_ + ch) * HW_ + x0 + 4 * xq));
            tile[ch][4 * xq + 0] = v.x; tile[ch][4 * xq + 1] = v.y;
            tile[ch][4 * xq + 2] = v.z; tile[ch][4 * xq + 3] = v.w;
        }
        __syncthreads();
        for (int i = tid; i < CHUNK_ * (C_ / 4); i += 256) {
            int p = i / 24, cq = i - p * 24;
            float4 v;
            v.x = tile[4 * cq + 0][p]; v.y = tile[4 * cq + 1][p];
            v.z = tile[4 * cq + 2][p]; v.w = tile[4 * cq + 3][p];
            *((float4*)(d + (pl * HW_ + x0 + p) * C_ + 4 * cq)) = v;
        }
    }
}

__global__ __launch_bounds__(256) void transp_kernel(
    const void* __restrict__ idxf, void* __restrict__ dst,
    const u32* __restrict__ detect_src)
{
    __shared__ __align__(16) char tileraw[C_ * (CHUNK_ + 1) * 4];
    __shared__ int s_flag;
    const int tid = threadIdx.x;
    const bool bf = block_detect_bf16(detect_src, tid, &s_flag);
    if (bf) transp_body<true >(idxf, dst, blockIdx.x, tid, tileraw);
    else    transp_body<false>(idxf, dst, blockIdx.x, tid, tileraw);
}

// ====================== KERNEL A: argmax (round-2 phases 1-7 verbatim) ======================
// Low LDS (14.6 KB) -> 8 blocks/CU (32 waves). Writes per-(pixel,head) {best, gbase} to ws.
template<bool BF16>
__device__ __forceinline__ void argmax_body(
    const void* __restrict__ curr, const void* __restrict__ loc,
    const void* __restrict__ kT,
    float* __restrict__ ws_best, int* __restrict__ ws_gbase,
    float* s_u, int (*s_lin)[P_], float (*s_red)[8],
    float (*s_best)[HEAD_], int (*s_bidx)[HEAD_], float* s_inv)
{
#define S_Q(pp, ch)  s_u[(pp) * QP_ + (ch)]
#define S_K(pp, ch)  s_u[P_ * QP_ + (pp) * QP_ + (ch)]
    const int tid = threadIdx.x;
    const int b  = blockIdx.x;
    const int nn = b / (HW_ / P_);
    const int p0 = (b - nn * (HW_ / P_)) * P_;

    // ---- nearest-sample indices (exact reference op sequence) ----
    if (tid < T_ * P_) {
        int t = tid / P_, pp = tid - t * P_;
        int p = p0 + pp;
        float x = ld1<BF16>(loc, (nn * 2 * T_ + 2 * t    ) * HW_ + p);
        float y = ld1<BF16>(loc, (nn * 2 * T_ + 2 * t + 1) * HW_ + p);
        float gx = 2.0f * x / 95.0f - 1.0f;
        float gy = 2.0f * y / 95.0f - 1.0f;
        float fx = (gx + 1.0f) * 0.5f * 95.0f;
        float fy = (gy + 1.0f) * 0.5f * 95.0f;
        float ix = rintf(fx), iy = rintf(fy);     // round-half-even == jnp.round
        bool v = (ix >= 0.0f) && (ix <= 95.0f) && (iy >= 0.0f) && (iy <= 95.0f);
        s_lin[t][pp] = v ? ((int)iy * W_ + (int)ix) : -1;
    }
    if (tid >= 128 && tid < 128 + P_ * HEAD_) {
        int q = tid - 128;
        s_best[q >> 2][q & 3] = -3.0e38f; s_bidx[q >> 2][q & 3] = 0;
    }

    // ---- load curr (float4 along pixels, coalesced) ----
    for (int i = tid; i < C_ * (P_ / 4); i += 256) {
        int ch = i >> 2, pq = i & 3;
        float w[4];
        ld4w<BF16>(curr, (nn * C_ + ch) * HW_ + p0 + 4 * pq, w);
        S_Q(4 * pq + 0, ch) = w[0]; S_Q(4 * pq + 1, ch) = w[1];
        S_Q(4 * pq + 2, ch) = w[2]; S_Q(4 * pq + 3, ch) = w[3];
    }
    __syncthreads();

    // ---- q L2 norm over full c (before head split) ----
    if (tid < P_ * 8) {
        int pp = tid >> 3, j = tid & 7;
        float s = 0.f;
        #pragma unroll
        for (int k = 0; k < 12; ++k) { float v = S_Q(pp, j * 12 + k); s += v * v; }
        s_red[pp][j] = s;
    }
    __syncthreads();
    if (tid < P_) {
        float s = 0.f;
        #pragma unroll
        for (int j = 0; j < 8; ++j) s += s_red[tid][j];
        s_inv[tid] = 1.0f / fmaxf(sqrtf(s), 1e-12f);
    }
    __syncthreads();
    for (int i = tid; i < C_ * P_; i += 256) {
        int pp = i & (P_ - 1), ch = i >> 4;
        S_Q(pp, ch) *= s_inv[pp];
    }

    // ---- per-frame: gather k (from transposed kT), normalize, dots, running argmax ----
    for (int t = 0; t < T_; ++t) {
        __syncthreads();
        for (int i = tid; i < 24 * P_; i += 256) {
            int pp = i / 24, j = i - pp * 24;
            int lin = s_lin[t][pp];
            float w[4] = {0.f, 0.f, 0.f, 0.f};
            if (lin >= 0) ld4w<BF16>(kT, ((nn * T_ + t) * HW_ + lin) * C_ + 4 * j, w);
            *((float4*)&S_K(pp, 4 * j)) = make_float4(w[0], w[1], w[2], w[3]);
        }
        __syncthreads();
        if (tid < P_ * 8) {
            int pp = tid >> 3, j = tid & 7;
            float s = 0.f;
            #pragma unroll
            for (int k = 0; k < 12; ++k) { float v = S_K(pp, j * 12 + k); s += v * v; }
            s_red[pp][j] = s;
        }
        __syncthreads();
        if (tid < P_) {
            float s = 0.f;
            #pragma unroll
            for (int j = 0; j < 8; ++j) s += s_red[tid][j];
            s_inv[tid] = 1.0f / fmaxf(sqrtf(s), 1e-12f);
        }
        __syncthreads();
        if (tid < P_ * HEAD_) {
            int pp = tid >> 2, h = tid & 3;
            float s = 0.f;
            #pragma unroll
            for (int dq = 0; dq < 6; ++dq) {
                const float4 kv = *((const float4*)&S_K(pp, h * HD_ + 4 * dq));
                const float4 qv = *((const float4*)&S_Q(pp, h * HD_ + 4 * dq));
                s += kv.x * qv.x; s += kv.y * qv.y; s += kv.z * qv.z; s += kv.w * qv.w;
            }
            s *= s_inv[pp];
            if (s > s_best[pp][h]) { s_best[pp][h] = s; s_bidx[pp][h] = t; }  // strict > == first-max
        }
    }
    // ---- write {best, gbase} to workspace (same threads own the state; no sync) ----
    if (tid < P_ * HEAD_) {
        int pp = tid >> 2, h = tid & 3;
        int bt = s_bidx[pp][h];
        int lin = s_lin[bt][pp];
        int g = (nn * HW_ + p0 + pp) * HEAD_ + h;
        ws_best[g]  = s_best[pp][h];
        ws_gbase[g] = (lin >= 0) ? ((nn * T_ + bt) * C_ * HW_ + lin) : -1;
    }
#undef S_Q
#undef S_K
}

__global__ __launch_bounds__(256, 8) void argmax_kernel(
    const void* __restrict__ curr, const void* __restrict__ loc,
    const void* __restrict__ kT,
    float* __restrict__ ws_best, int* __restrict__ ws_gbase)
{
    __shared__ __align__(16) float s_u[2 * P_ * QP_];   // q | k  (12.8 KB)
    __shared__ int   s_lin[T_][P_];
    __shared__ float s_red[P_][8];
    __shared__ float s_best[P_][HEAD_];
    __shared__ int   s_bidx[P_][HEAD_];
    __shared__ float s_inv[P_];
    __shared__ int   s_flag;
    const bool bf = block_detect_bf16((const u32*)curr, threadIdx.x, &s_flag);
    if (bf) argmax_body<true >(curr, loc, kT, ws_best, ws_gbase, s_u, s_lin, s_red, s_best, s_bidx, s_inv);
    else    argmax_body<false>(curr, loc, kT, ws_best, ws_gbase, s_u, s_lin, s_red, s_best, s_bidx, s_inv);
}

// ====================== KERNEL B: cat gather + GEMVs (round-2 phases 8-10) ======================
// GEMVs widened to 192 active threads (2co x 4px register tile); per-output FP chains unchanged.
template<bool BF16>
__device__ __forceinline__ void catgemv_body(
    const void* __restrict__ anchor, const void* __restrict__ s1,
    const void* __restrict__ s2, const void* __restrict__ s3,
    const void* __restrict__ pw, const void* __restrict__ pb,
    const void* __restrict__ fw, const void* __restrict__ fb,
    void* __restrict__ outp,
    const float* __restrict__ ws_best, const int* __restrict__ ws_gbase,
    float* s_u, float (*s_mid)[QP_], float (*s_best)[HEAD_], int (*s_gbase)[HEAD_])
{
#define S_CAT(pp, d) s_u[(pp) * CATP_ + (d)]
    const int tid = threadIdx.x;
    const int b  = blockIdx.x;
    const int nn = b / (HW_ / P_);
    const int p0 = (b - nn * (HW_ / P_)) * P_;

    if (tid < P_ * HEAD_) {
        int pp = tid >> 2, h = tid & 3;
        int g = (nn * HW_ + p0 + pp) * HEAD_ + h;
        s_best[pp][h]  = ws_best[g];
        s_gbase[pp][h] = ws_gbase[g];
    }
    __syncthreads();

    // ---- scattered cat gather (precomputed bases) ----
    for (int i = tid; i < C3_ * P_; i += 256) {
        int pp = i / C3_, d = i - pp * C3_;
        int set = d / C_, ch = d - set * C_;
        int gb = s_gbase[pp][ch / HD_];
        float v = 0.f;
        if (gb >= 0) {
            const void* sp = (set == 0) ? s1 : (set == 1) ? s2 : s3;
            v = ld1<BF16>(sp, gb + ch * HW_);
        }
        S_CAT(pp, d) = v;
    }
    __syncthreads();

    // ---- fusion GEMV (96 x 288): 192 threads, 2co x 4px; same d-ascending chain ----
    if (tid < 192) {
        const int cp = tid >> 2, pq = tid & 3;
        const int co0 = cp * 2, px0 = pq * 4;
        float acc[2][4];
        #pragma unroll
        for (int r = 0; r < 2; ++r)
            #pragma unroll
            for (int k = 0; k < 4; ++k) acc[r][k] = 0.f;
        for (int d = 0; d < C3_; d += 4) {
            float4 cv[4];
            #pragma unroll
            for (int k = 0; k < 4; ++k) cv[k] = *((const float4*)&S_CAT(px0 + k, d));
            #pragma unroll
            for (int r = 0; r < 2; ++r) {
                float w[4]; ld4w<BF16>(fw, (co0 + r) * C3_ + d, w);
                #pragma unroll
                for (int k = 0; k < 4; ++k)
                    acc[r][k] += w[0] * cv[k].x + w[1] * cv[k].y + w[2] * cv[k].z + w[3] * cv[k].w;
            }
        }
        const int hh = co0 / HD_;   // co pairs never straddle a head (24 even)
        #pragma unroll
        for (int r = 0; r < 2; ++r) {
            float fbv = ld1<BF16>(fb, co0 + r);
            #pragma unroll
            for (int k = 0; k < 4; ++k)
                s_mid[px0 + k][co0 + r] = (acc[r][k] + fbv) * s_best[px0 + k][hh];
        }
    }
    __syncthreads();

    // ---- proj GEMV (96 x 96) + bias + anchor: 192 threads, 2co x 4px ----
    if (tid < 192) {
        const int dp = tid >> 2, pq = tid & 3;
        const int do0 = dp * 2, px0 = pq * 4;
        float acc[2][4];
        #pragma unroll
        for (int r = 0; r < 2; ++r)
            #pragma unroll
            for (int k = 0; k < 4; ++k) acc[r][k] = 0.f;
        for (int c = 0; c < C_; c += 4) {
            float4 mv[4];
            #pragma unroll
            for (int k = 0; k < 4; ++k) mv[k] = *((const float4*)&s_mid[px0 + k][c]);
            #pragma unroll
            for (int r = 0; r < 2; ++r) {
                float w[4]; ld4w<BF16>(pw, (do0 + r) * C_ + c, w);
                #pragma unroll
                for (int k = 0; k < 4; ++k)
                    acc[r][k] += w[0] * mv[k].x + w[1] * mv[k].y + w[2] * mv[k].z + w[3] * mv[k].w;
            }
        }
        #pragma unroll
        for (int r = 0; r < 2; ++r) {
            float pbv = ld1<BF16>(pb, do0 + r);
            float av[4];
            ld4w<BF16>(anchor, (nn * C_ + do0 + r) * HW_ + p0 + px0, av);
            float res[4];
            #pragma unroll
            for (int k = 0; k < 4; ++k) res[k] = acc[r][k] + pbv + av[k];
            st4w<BF16>(outp, (nn * C_ + do0 + r) * HW_ + p0 + px0, res);
        }
    }
#undef S_CAT
}

__global__ __launch_bounds__(256, 6) void catgemv_kernel(
    const void* __restrict__ curr, const void* __restrict__ anchor,
    const void* __restrict__ s1, const void* __restrict__ s2,
    const void* __restrict__ s3, const void* __restrict__ pw,
    const void* __restrict__ pb, const void* __restrict__ fw,
    const void* __restrict__ fb, void* __restrict__ outp,
    const float* __restrict__ ws_best, const int* __restrict__ ws_gbase)
{
    __shared__ __align__(16) float s_u[P_ * CATP_];   // 18.7 KB
    __shared__ __align__(16) float s_mid[P_][QP_];    // 6.4 KB
    __shared__ float s_best[P_][HEAD_];
    __shared__ int   s_gbase[P_][HEAD_];
    __shared__ int   s_flag;
    const bool bf = block_detect_bf16((const u32*)curr, threadIdx.x, &s_flag);
    if (bf) catgemv_body<true >(anchor, s1, s2, s3, pw, pb, fw, fb, outp, ws_best, ws_gbase,
                                s_u, s_mid, s_best, s_gbase);
    else    catgemv_body<false>(anchor, s1, s2, s3, pw, pb, fw, fb, outp, ws_best, ws_gbase,
                                s_u, s_mid, s_best, s_gbase);
}

// ====================== monolithic MODE-0 fallback (round-2 verbatim, scattered k) ======================
template<bool BF16>
__device__ __forceinline__ void mono_body(
    const void* __restrict__ curr, const void* __restrict__ idxf,
    const void* __restrict__ anchor, const void* __restrict__ s1,
    const void* __restrict__ s2, const void* __restrict__ s3,
    const void* __restrict__ loc, const void* __restrict__ pw,
    const void* __restrict__ pb, const void* __restrict__ fw,
    const void* __restrict__ fb, void* __restrict__ outp,
    float* s_u, float (*s_mid)[QP_], int (*s_lin)[P_], float (*s_red)[8],
    float (*s_best)[HEAD_], int (*s_bidx)[HEAD_], float* s_inv)
{
#define S_Q(pp, ch)  s_u[(pp) * QP_ + (ch)]
#define S_K(pp, ch)  s_u[P_ * QP_ + (pp) * QP_ + (ch)]
#define S_CAT(pp, d) s_u[(pp) * CATP_ + (d)]
    const int tid = threadIdx.x;
    const int b  = blockIdx.x;
    const int nn = b / (HW_ / P_);
    const int p0 = (b - nn * (HW_ / P_)) * P_;

    if (tid < T_ * P_) {
        int t = tid / P_, pp = tid - t * P_;
        int p = p0 + pp;
        float x = ld1<BF16>(loc, (nn * 2 * T_ + 2 * t    ) * HW_ + p);
        float y = ld1<BF16>(loc, (nn * 2 * T_ + 2 * t + 1) * HW_ + p);
        float gx = 2.0f * x / 95.0f - 1.0f;
        float gy = 2.0f * y / 95.0f - 1.0f;
        float fx = (gx + 1.0f) * 0.5f * 95.0f;
        float fy = (gy + 1.0f) * 0.5f * 95.0f;
        float ix = rintf(fx), iy = rintf(fy);
        bool v = (ix >= 0.0f) && (ix <= 95.0f) && (iy >= 0.0f) && (iy <= 95.0f);
        s_lin[t][pp] = v ? ((int)iy * W_ + (int)ix) : -1;
    }
    if (tid >= 128 && tid < 128 + P_ * HEAD_) {
        int q = tid - 128;
        s_best[q >> 2][q & 3] = -3.0e38f; s_bidx[q >> 2][q & 3] = 0;
    }
    for (int i = tid; i < C_ * (P_ / 4); i += 256) {
        int ch = i >> 2, pq = i & 3;
        float w[4];
        ld4w<BF16>(curr, (nn * C_ + ch) * HW_ + p0 + 4 * pq, w);
        S_Q(4 * pq + 0, ch) = w[0]; S_Q(4 * pq + 1, ch) = w[1];
        S_Q(4 * pq + 2, ch) = w[2]; S_Q(4 * pq + 3, ch) = w[3];
    }
    __syncthreads();
    if (tid < P_ * 8) {
        int pp = tid >> 3, j = tid & 7;
        float s = 0.f;
        #pragma unroll
        for (int k = 0; k < 12; ++k) { float v = S_Q(pp, j * 12 + k); s += v * v; }
        s_red[pp][j] = s;
    }
    __syncthreads();
    if (tid < P_) {
        float s = 0.f;
        #pragma unroll
        for (int j = 0; j < 8; ++j) s += s_red[tid][j];
        s_inv[tid] = 1.0f / fmaxf(sqrtf(s), 1e-12f);
    }
    __syncthreads();
    for (int i = tid; i < C_ * P_; i += 256) {
        int pp = i & (P_ - 1), ch = i >> 4;
        S_Q(pp, ch) *= s_inv[pp];
    }
    for (int t = 0; t < T_; ++t) {
        __syncthreads();
        for (int i = tid; i < C_ * P_; i += 256) {
            int ch = i / P_, pp = i - ch * P_;
            int lin = s_lin[t][pp];
            S_K(pp, ch) = (lin >= 0) ? ld1<BF16>(idxf, ((nn * T_ + t) * C_ + ch) * HW_ + lin) : 0.0f;
        }
        __syncthreads();
        if (tid < P_ * 8) {
            int pp = tid >> 3, j = tid & 7;
            float s = 0.f;
            #pragma unroll
            for (int k = 0; k < 12; ++k) { float v = S_K(pp, j * 12 + k); s += v * v; }
            s_red[pp][j] = s;
        }
        __syncthreads();
        if (tid < P_) {
            float s = 0.f;
            #pragma unroll
            for (int j = 0; j < 8; ++j) s += s_red[tid][j];
            s_inv[tid] = 1.0f / fmaxf(sqrtf(s), 1e-12f);
        }
        __syncthreads();
        if (tid < P_ * HEAD_) {
            int pp = tid >> 2, h = tid & 3;
            float s = 0.f;
            #pragma unroll
            for (int dq = 0; dq < 6; ++dq) {
                const float4 kv = *((const float4*)&S_K(pp, h * HD_ + 4 * dq));
                const float4 qv = *((const float4*)&S_Q(pp, h * HD_ + 4 * dq));
                s += kv.x * qv.x; s += kv.y * qv.y; s += kv.z * qv.z; s += kv.w * qv.w;
            }
            s *= s_inv[pp];
            if (s > s_best[pp][h]) { s_best[pp][h] = s; s_bidx[pp][h] = t; }
        }
    }
    __syncthreads();
    for (int i = tid; i < C3_ * P_; i += 256) {
        int pp = i / C3_, d = i - pp * C3_;
        int set = d / C_, ch = d - set * C_;
        int h = ch / HD_;
        int bt = s_bidx[pp][h];
        int lin = s_lin[bt][pp];
        float v = 0.f;
        if (lin >= 0) {
            const void* sp = (set == 0) ? s1 : (set == 1) ? s2 : s3;
            v = ld1<BF16>(sp, ((nn * T_ + bt) * C_ + ch) * HW_ + lin);
        }
        S_CAT(pp, d) = v;
    }
    __syncthreads();
    if (tid < 96) {
        const int cq = tid >> 2, pq = tid & 3;
        const int co0 = cq * 4, px0 = pq * 4;
        float acc[4][4];
        #pragma unroll
        for (int r = 0; r < 4; ++r)
            #pragma unroll
            for (int k = 0; k < 4; ++k) acc[r][k] = 0.f;
        for (int d = 0; d < C3_; d += 4) {
            float4 cv[4];
            #pragma unroll
            for (int k = 0; k < 4; ++k) cv[k] = *((const float4*)&S_CAT(px0 + k, d));
            #pragma unroll
            for (int r = 0; r < 4; ++r) {
                float w[4]; ld4w<BF16>(fw, (co0 + r) * C3_ + d, w);
                #pragma unroll
                for (int k = 0; k < 4; ++k)
                    acc[r][k] += w[0] * cv[k].x + w[1] * cv[k].y + w[2] * cv[k].z + w[3] * cv[k].w;
            }
        }
        const int hh = co0 / HD_;
        #pragma unroll
        for (int r = 0; r < 4; ++r) {
            float fbv = ld1<BF16>(fb, co0 + r);
            #pragma unroll
            for (int k = 0; k < 4; ++k)
                s_mid[px0 + k][co0 + r] = (acc[r][k] + fbv) * s_best[px0 + k][hh];
        }
    }
    __syncthreads();
    if (tid < 96) {
        const int dq = tid >> 2, pq = tid & 3;
        const int do0 = dq * 4, px0 = pq * 4;
        float acc[4][4];
        #pragma unroll
        for (int r = 0; r < 4; ++r)
            #pragma unroll
            for (int k = 0; k < 4; ++k) acc[r][k] = 0.f;
        for (int c = 0; c < C_; c += 4) {
            float4 mv[4];
            #pragma unroll
            for (int k = 0; k < 4; ++k) mv[k] = *((const float4*)&s_mid[px0 + k][c]);
            #pragma unroll
            for (int r = 0; r < 4; ++r) {
                float w[4]; ld4w<BF16>(pw, (do0 + r) * C_ + c, w);
                #pragma unroll
                for (int k = 0; k < 4; ++k)
                    acc[r][k] += w[0] * mv[k].x + w[1] * mv[k].y + w[2] * mv[k].z + w[3] * mv[k].w;
            }
        }
        #pragma unroll
        for (int r = 0; r < 4; ++r) {
            float pbv = ld1<BF16>(pb, do0 + r);
            float av[4];
            ld4w<BF16>(anchor, (nn * C_ + do0 + r) * HW_ + p0 + px0, av);
            float res[4];
            #pragma unroll
            for (int k = 0; k < 4; ++k) res[k] = acc[r][k] + pbv + av[k];
            st4w<BF16>(outp, (nn * C_ + do0 + r) * HW_ + p0 + px0, res);
        }
    }
#undef S_Q
#undef S_K
#undef S_CAT
}

__global__ __launch_bounds__(256) void mono_kernel(
    const void* __restrict__ curr, const void* __restrict__ idxf,
    const void* __restrict__ anchor, const void* __restrict__ s1,
    const void* __restrict__ s2, const void* __restrict__ s3,
    const void* __restrict__ loc, const void* __restrict__ pw,
    const void* __restrict__ pb, const void* __restrict__ fw,
    const void* __restrict__ fb, void* __restrict__ outp)
{
    __shared__ __align__(16) float s_u[P_ * CATP_];
    __shared__ __align__(16) float s_mid[P_][QP_];
    __shared__ int   s_lin[T_][P_];
    __shared__ float s_red[P_][8];
    __shared__ float s_best[P_][HEAD_];
    __shared__ int   s_bidx[P_][HEAD_];
    __shared__ float s_inv[P_];
    __shared__ int   s_flag;
    const bool bf = block_detect_bf16((const u32*)curr, threadIdx.x, &s_flag);
    if (bf) mono_body<true >(curr, idxf, anchor, s1, s2, s3, loc, pw, pb, fw, fb, outp,
                             s_u, s_mid, s_lin, s_red, s_best, s_bidx, s_inv);
    else    mono_body<false>(curr, idxf, anchor, s1, s2, s3, loc, pw, pb, fw, fb, outp,
                             s_u, s_mid, s_lin, s_red, s_best, s_bidx, s_inv);
}

extern "C" void kernel_launch(void* const* d_in, const int* in_sizes, int n_in,
                              void* d_out, int out_size, void* d_ws, size_t ws_size,
                              hipStream_t stream) {
    (void)in_sizes; (void)n_in; (void)out_size;
    const unsigned long long SZB  = (unsigned long long)N_ * T_ * HW_ * C_ * 4ull; // 49.5 MB (f32 worst case)
    const unsigned long long AUXB = (unsigned long long)N_ * HW_ * HEAD_ * 4ull;   // 294,912 B each
    char* wsb = (char*)d_ws;
    void*  kT       = wsb;
    float* ws_best  = (float*)(wsb + SZB);
    int*   ws_gbase = (int*)  (wsb + SZB + AUXB);

    dim3 grid(NBLK_), block(256);
    if (ws_size >= SZB + 2 * AUXB) {
        transp_kernel<<<dim3(PLANES_ * NCHUNK_), 256, 0, stream>>>(d_in[1], kT, (const u32*)d_in[0]);
        argmax_kernel<<<grid, block, 0, stream>>>(d_in[0], d_in[6], kT, ws_best, ws_gbase);
        catgemv_kernel<<<grid, block, 0, stream>>>(d_in[0], d_in[2], d_in[3], d_in[4], d_in[5],
                                                   d_in[7], d_in[8], d_in[9], d_in[10], d_out,
                                                   ws_best, ws_gbase);
    } else {
        mono_kernel<<<grid, block, 0, stream>>>(d_in[0], d_in[1], d_in[2], d_in[3], d_in[4],
                                                d_in[5], d_in[6], d_in[7], d_in[8], d_in[9],
                                                d_in[10], d_out);
    }
}

// Round 7
// 311.960 us; speedup vs baseline: 1.2776x; 1.0375x over previous
//
#include <hip/hip_runtime.h>
#include <hip/hip_bf16.h>

#define N_    2
#define T_    7
#define C_    96
#define H_    96
#define W_    96
#define HW_   9216
#define HEAD_ 4
#define HD_   24
#define C3_   288
#define P_    16           // pixels per block: grid 1152, 256 threads, full-line output stores
#define QP_   100          // padded row stride for q/k tiles (mult of 4 -> 16B-aligned)
#define CATP_ 292          // padded row stride for cat tile (mult of 4)
#define NBLK_ (N_ * (HW_ / P_))   // 1152
#define PLANES_ 14         // n*t
#define CHUNK_  64
#define NCHUNK_ 144        // 9216/64

typedef unsigned int u32;

__device__ __forceinline__ float bits2f(u32 b) {
    union { u32 u; float f; } x; x.u = b; return x.f;
}

__device__ __forceinline__ unsigned short f2bf(float f) {
    union { __hip_bfloat16 h; unsigned short s; } u;
    u.h = __float2bfloat16(f);
    return u.s;
}

template<bool BF16>
__device__ __forceinline__ float ld1(const void* p, int i) {
    if constexpr (BF16) return bits2f(((u32)((const unsigned short*)p)[i]) << 16);
    else                return ((const float*)p)[i];
}

// load 4 consecutive elements starting at i (i % 4 == 0)
template<bool BF16>
__device__ __forceinline__ void ld4w(const void* p, int i, float w[4]) {
    if constexpr (BF16) {
        const uint2 u = ((const uint2*)p)[i >> 2];
        w[0] = bits2f(u.x << 16);
        w[1] = bits2f(u.x & 0xFFFF0000u);
        w[2] = bits2f(u.y << 16);
        w[3] = bits2f(u.y & 0xFFFF0000u);
    } else {
        const float4 v = *((const float4*)((const float*)p + i));
        w[0] = v.x; w[1] = v.y; w[2] = v.z; w[3] = v.w;
    }
}

template<bool BF16>
__device__ __forceinline__ void st1(void* p, int i, float v) {
    if constexpr (BF16) ((unsigned short*)p)[i] = f2bf(v);
    else                ((float*)p)[i] = v;
}

// store 4 consecutive elements starting at i (i % 4 == 0)
template<bool BF16>
__device__ __forceinline__ void st4w(void* p, int i, const float v[4]) {
    if constexpr (BF16) {
        uint2 w;
        w.x = (u32)f2bf(v[0]) | ((u32)f2bf(v[1]) << 16);
        w.y = (u32)f2bf(v[2]) | ((u32)f2bf(v[3]) << 16);
        ((uint2*)p)[i >> 2] = w;
    } else {
        *((float4*)((float*)p + i)) = make_float4(v[0], v[1], v[2], v[3]);
    }
}

// ---- per-block dtype detect: deterministic, same rule everywhere ----
__device__ __forceinline__ bool block_detect_bf16(const u32* __restrict__ w,
                                                  int tid, int* s_flag) {
    if (tid < 64) {
        u32 x = w[tid];
        u32 f = x & 0x7FFFu;
        int inwin = (f >= 0x3A00u) && (f <= 0x4200u);
        unsigned long long m = __ballot(inwin);
        if (tid == 0) *s_flag = (__popcll(m) >= 40) ? 1 : 0;
    }
    __syncthreads();
    return *s_flag != 0;
}

// ---- (c,hw) -> (hw,c) transpose per (n*t) plane, bit-exact copy.
// blockIdx.x = plane*NCHUNK_ + chunk; blockIdx.y = which array (0=idxf,1..3=s1..s3)
template<bool BF16>
__device__ __forceinline__ void transp_body(const void* __restrict__ src,
                                            void* __restrict__ dst,
                                            int bx, int tid, char* tileraw) {
    const int pl = bx / NCHUNK_;
    const int x0 = (bx - pl * NCHUNK_) * CHUNK_;
    if constexpr (BF16) {
        unsigned short (*tile)[CHUNK_ + 2] = (unsigned short (*)[CHUNK_ + 2])tileraw;
        const unsigned short* s = (const unsigned short*)src;
        unsigned short* d = (unsigned short*)dst;
        for (int i = tid; i < C_ * (CHUNK_ / 4); i += 256) {
            int ch = i >> 4, xq = i & 15;
            const ushort4 v = *((const ushort4*)(s + (pl * C_ + ch) * HW_ + x0 + 4 * xq));
            tile[ch][4 * xq + 0] = v.x; tile[ch][4 * xq + 1] = v.y;
            tile[ch][4 * xq + 2] = v.z; tile[ch][4 * xq + 3] = v.w;
        }
        __syncthreads();
        for (int i = tid; i < CHUNK_ * (C_ / 4); i += 256) {
            int p = i / 24, cq = i - p * 24;
            ushort4 v;
            v.x = tile[4 * cq + 0][p]; v.y = tile[4 * cq + 1][p];
            v.z = tile[4 * cq + 2][p]; v.w = tile[4 * cq + 3][p];
            *((ushort4*)(d + (pl * HW_ + x0 + p) * C_ + 4 * cq)) = v;
        }
    } else {
        float (*tile)[CHUNK_ + 1] = (float (*)[CHUNK_ + 1])tileraw;
        const float* s = (const float*)src;
        float* d = (float*)dst;
        for (int i = tid; i < C_ * (CHUNK_ / 4); i += 256) {
            int ch = i >> 4, xq = i & 15;
            const float4 v = *((const float4*)(s + (pl * C_ + ch) * HW_ + x0 + 4 * xq));
            tile[ch][4 * xq + 0] = v.x; tile[ch][4 * xq + 1] = v.y;
            tile[ch][4 * xq + 2] = v.z; tile[ch][4 * xq + 3] = v.w;
        }
        __syncthreads();
        for (int i = tid; i < CHUNK_ * (C_ / 4); i += 256) {
            int p = i / 24, cq = i - p * 24;
            float4 v;
            v.x = tile[4 * cq + 0][p]; v.y = tile[4 * cq + 1][p];
            v.z = tile[4 * cq + 2][p]; v.w = tile[4 * cq + 3][p];
            *((float4*)(d + (pl * HW_ + x0 + p) * C_ + 4 * cq)) = v;
        }
    }
}

__global__ __launch_bounds__(256) void transp_kernel(
    const void* __restrict__ a0, const void* __restrict__ a1,
    const void* __restrict__ a2, const void* __restrict__ a3,
    void* __restrict__ dstb, unsigned long long szb,
    const u32* __restrict__ detect_src)
{
    __shared__ __align__(16) char tileraw[C_ * (CHUNK_ + 1) * 4];
    __shared__ int s_flag;
    const int arr = blockIdx.y;
    const void* src = (arr == 0) ? a0 : (arr == 1) ? a1 : (arr == 2) ? a2 : a3;
    void* dst = (char*)dstb + (unsigned long long)arr * szb;
    const int tid = threadIdx.x;
    const bool bf = block_detect_bf16(detect_src, tid, &s_flag);
    if (bf) transp_body<true >(src, dst, blockIdx.x, tid, tileraw);
    else    transp_body<false>(src, dst, blockIdx.x, tid, tileraw);
}

// ====================== KERNEL A: argmax (round-2 phases 1-7 verbatim) ======================
// Low LDS (14.6 KB) -> 8 blocks/CU. Writes per-(pixel,head) {best, gbase} to ws.
// TGB: gather base in transposed coords (for s123T cat gather) vs original coords.
template<bool BF16, bool TGB>
__device__ __forceinline__ void argmax_body(
    const void* __restrict__ curr, const void* __restrict__ loc,
    const void* __restrict__ kT,
    float* __restrict__ ws_best, int* __restrict__ ws_gbase,
    float* s_u, int (*s_lin)[P_], float (*s_red)[8],
    float (*s_best)[HEAD_], int (*s_bidx)[HEAD_], float* s_inv)
{
#define S_Q(pp, ch)  s_u[(pp) * QP_ + (ch)]
#define S_K(pp, ch)  s_u[P_ * QP_ + (pp) * QP_ + (ch)]
    const int tid = threadIdx.x;
    const int b  = blockIdx.x;
    const int nn = b / (HW_ / P_);
    const int p0 = (b - nn * (HW_ / P_)) * P_;

    // ---- nearest-sample indices (exact reference op sequence) ----
    if (tid < T_ * P_) {
        int t = tid / P_, pp = tid - t * P_;
        int p = p0 + pp;
        float x = ld1<BF16>(loc, (nn * 2 * T_ + 2 * t    ) * HW_ + p);
        float y = ld1<BF16>(loc, (nn * 2 * T_ + 2 * t + 1) * HW_ + p);
        float gx = 2.0f * x / 95.0f - 1.0f;
        float gy = 2.0f * y / 95.0f - 1.0f;
        float fx = (gx + 1.0f) * 0.5f * 95.0f;
        float fy = (gy + 1.0f) * 0.5f * 95.0f;
        float ix = rintf(fx), iy = rintf(fy);     // round-half-even == jnp.round
        bool v = (ix >= 0.0f) && (ix <= 95.0f) && (iy >= 0.0f) && (iy <= 95.0f);
        s_lin[t][pp] = v ? ((int)iy * W_ + (int)ix) : -1;
    }
    if (tid >= 128 && tid < 128 + P_ * HEAD_) {
        int q = tid - 128;
        s_best[q >> 2][q & 3] = -3.0e38f; s_bidx[q >> 2][q & 3] = 0;
    }

    // ---- load curr (float4 along pixels, coalesced) ----
    for (int i = tid; i < C_ * (P_ / 4); i += 256) {
        int ch = i >> 2, pq = i & 3;
        float w[4];
        ld4w<BF16>(curr, (nn * C_ + ch) * HW_ + p0 + 4 * pq, w);
        S_Q(4 * pq + 0, ch) = w[0]; S_Q(4 * pq + 1, ch) = w[1];
        S_Q(4 * pq + 2, ch) = w[2]; S_Q(4 * pq + 3, ch) = w[3];
    }
    __syncthreads();

    // ---- q L2 norm over full c (before head split) ----
    if (tid < P_ * 8) {
        int pp = tid >> 3, j = tid & 7;
        float s = 0.f;
        #pragma unroll
        for (int k = 0; k < 12; ++k) { float v = S_Q(pp, j * 12 + k); s += v * v; }
        s_red[pp][j] = s;
    }
    __syncthreads();
    if (tid < P_) {
        float s = 0.f;
        #pragma unroll
        for (int j = 0; j < 8; ++j) s += s_red[tid][j];
        s_inv[tid] = 1.0f / fmaxf(sqrtf(s), 1e-12f);
    }
    __syncthreads();
    for (int i = tid; i < C_ * P_; i += 256) {
        int pp = i & (P_ - 1), ch = i >> 4;
        S_Q(pp, ch) *= s_inv[pp];
    }

    // ---- per-frame: gather k (from transposed kT), normalize, dots, running argmax ----
    for (int t = 0; t < T_; ++t) {
        __syncthreads();
        for (int i = tid; i < 24 * P_; i += 256) {
            int pp = i / 24, j = i - pp * 24;
            int lin = s_lin[t][pp];
            float w[4] = {0.f, 0.f, 0.f, 0.f};
            if (lin >= 0) ld4w<BF16>(kT, ((nn * T_ + t) * HW_ + lin) * C_ + 4 * j, w);
            *((float4*)&S_K(pp, 4 * j)) = make_float4(w[0], w[1], w[2], w[3]);
        }
        __syncthreads();
        if (tid < P_ * 8) {
            int pp = tid >> 3, j = tid & 7;
            float s = 0.f;
            #pragma unroll
            for (int k = 0; k < 12; ++k) { float v = S_K(pp, j * 12 + k); s += v * v; }
            s_red[pp][j] = s;
        }
        __syncthreads();
        if (tid < P_) {
            float s = 0.f;
            #pragma unroll
            for (int j = 0; j < 8; ++j) s += s_red[tid][j];
            s_inv[tid] = 1.0f / fmaxf(sqrtf(s), 1e-12f);
        }
        __syncthreads();
        if (tid < P_ * HEAD_) {
            int pp = tid >> 2, h = tid & 3;
            float s = 0.f;
            #pragma unroll
            for (int dq = 0; dq < 6; ++dq) {
                const float4 kv = *((const float4*)&S_K(pp, h * HD_ + 4 * dq));
                const float4 qv = *((const float4*)&S_Q(pp, h * HD_ + 4 * dq));
                s += kv.x * qv.x; s += kv.y * qv.y; s += kv.z * qv.z; s += kv.w * qv.w;
            }
            s *= s_inv[pp];
            if (s > s_best[pp][h]) { s_best[pp][h] = s; s_bidx[pp][h] = t; }  // strict > == first-max
        }
    }
    // ---- write {best, gbase} to workspace (same threads own the state; no sync) ----
    if (tid < P_ * HEAD_) {
        int pp = tid >> 2, h = tid & 3;
        int bt = s_bidx[pp][h];
        int lin = s_lin[bt][pp];
        int g = (nn * HW_ + p0 + pp) * HEAD_ + h;
        ws_best[g] = s_best[pp][h];
        int gb;
        if (lin < 0)       gb = -1;
        else if (TGB)      gb = ((nn * T_ + bt) * HW_ + lin) * C_;   // transposed (hw,c) coords
        else               gb = (nn * T_ + bt) * C_ * HW_ + lin;     // original (c,hw) coords
        ws_gbase[g] = gb;
    }
#undef S_Q
#undef S_K
}

template<bool TGB>
__global__ __launch_bounds__(256, 8) void argmax_kernel(
    const void* __restrict__ curr, const void* __restrict__ loc,
    const void* __restrict__ kT,
    float* __restrict__ ws_best, int* __restrict__ ws_gbase)
{
    __shared__ __align__(16) float s_u[2 * P_ * QP_];   // q | k  (12.8 KB)
    __shared__ int   s_lin[T_][P_];
    __shared__ float s_red[P_][8];
    __shared__ float s_best[P_][HEAD_];
    __shared__ int   s_bidx[P_][HEAD_];
    __shared__ float s_inv[P_];
    __shared__ int   s_flag;
    const bool bf = block_detect_bf16((const u32*)curr, threadIdx.x, &s_flag);
    if (bf) argmax_body<true , TGB>(curr, loc, kT, ws_best, ws_gbase, s_u, s_lin, s_red, s_best, s_bidx, s_inv);
    else    argmax_body<false, TGB>(curr, loc, kT, ws_best, ws_gbase, s_u, s_lin, s_red, s_best, s_bidx, s_inv);
}

// ====================== KERNEL B: cat gather + GEMVs ======================
// TRANS=1: gather cat from transposed s123T (float4, ~2 lines per 24-ch chunk).
// TRANS=0: round-6 scattered gather from original layout. Values bit-identical.
template<bool BF16, bool TRANS>
__device__ __forceinline__ void catgemv_body(
    const void* __restrict__ anchor, const void* __restrict__ s1,
    const void* __restrict__ s2, const void* __restrict__ s3,
    const void* __restrict__ pw, const void* __restrict__ pb,
    const void* __restrict__ fw, const void* __restrict__ fb,
    void* __restrict__ outp,
    const float* __restrict__ ws_best, const int* __restrict__ ws_gbase,
    float* s_u, float (*s_mid)[QP_], float (*s_best)[HEAD_], int (*s_gbase)[HEAD_])
{
#define S_CAT(pp, d) s_u[(pp) * CATP_ + (d)]
    const int tid = threadIdx.x;
    const int b  = blockIdx.x;
    const int nn = b / (HW_ / P_);
    const int p0 = (b - nn * (HW_ / P_)) * P_;

    if (tid < P_ * HEAD_) {
        int pp = tid >> 2, h = tid & 3;
        int g = (nn * HW_ + p0 + pp) * HEAD_ + h;
        s_best[pp][h]  = ws_best[g];
        s_gbase[pp][h] = ws_gbase[g];
    }
    __syncthreads();

    // ---- cat gather ----
    if constexpr (TRANS) {
        // transposed layout: per (px,set): 24 float4 chunks, channel-contiguous
        for (int i = tid; i < P_ * 72; i += 256) {
            int px = i / 72, j = i - px * 72;
            int set = j / 24, jj = j - set * 24;        // ch = 4*jj
            int gb = s_gbase[px][jj / 6];               // head = (4*jj)/24
            float w[4] = {0.f, 0.f, 0.f, 0.f};
            if (gb >= 0) {
                const void* sp = (set == 0) ? s1 : (set == 1) ? s2 : s3;
                ld4w<BF16>(sp, gb + 4 * jj, w);
            }
            *((float4*)&S_CAT(px, set * C_ + 4 * jj)) = make_float4(w[0], w[1], w[2], w[3]);
        }
    } else {
        for (int i = tid; i < C3_ * P_; i += 256) {
            int pp = i / C3_, d = i - pp * C3_;
            int set = d / C_, ch = d - set * C_;
            int gb = s_gbase[pp][ch / HD_];
            float v = 0.f;
            if (gb >= 0) {
                const void* sp = (set == 0) ? s1 : (set == 1) ? s2 : s3;
                v = ld1<BF16>(sp, gb + ch * HW_);
            }
            S_CAT(pp, d) = v;
        }
    }
    __syncthreads();

    // ---- fusion GEMV (96 x 288): 192 threads, 2co x 4px; same d-ascending chain ----
    if (tid < 192) {
        const int cp = tid >> 2, pq = tid & 3;
        const int co0 = cp * 2, px0 = pq * 4;
        float acc[2][4];
        #pragma unroll
        for (int r = 0; r < 2; ++r)
            #pragma unroll
            for (int k = 0; k < 4; ++k) acc[r][k] = 0.f;
        for (int d = 0; d < C3_; d += 4) {
            float4 cv[4];
            #pragma unroll
            for (int k = 0; k < 4; ++k) cv[k] = *((const float4*)&S_CAT(px0 + k, d));
            #pragma unroll
            for (int r = 0; r < 2; ++r) {
                float w[4]; ld4w<BF16>(fw, (co0 + r) * C3_ + d, w);
                #pragma unroll
                for (int k = 0; k < 4; ++k)
                    acc[r][k] += w[0] * cv[k].x + w[1] * cv[k].y + w[2] * cv[k].z + w[3] * cv[k].w;
            }
        }
        const int hh = co0 / HD_;   // co pairs never straddle a head (24 even)
        #pragma unroll
        for (int r = 0; r < 2; ++r) {
            float fbv = ld1<BF16>(fb, co0 + r);
            #pragma unroll
            for (int k = 0; k < 4; ++k)
                s_mid[px0 + k][co0 + r] = (acc[r][k] + fbv) * s_best[px0 + k][hh];
        }
    }
    __syncthreads();

    // ---- proj GEMV (96 x 96) + bias + anchor: 192 threads, 2co x 4px ----
    if (tid < 192) {
        const int dp = tid >> 2, pq = tid & 3;
        const int do0 = dp * 2, px0 = pq * 4;
        float acc[2][4];
        #pragma unroll
        for (int r = 0; r < 2; ++r)
            #pragma unroll
            for (int k = 0; k < 4; ++k) acc[r][k] = 0.f;
        for (int c = 0; c < C_; c += 4) {
            float4 mv[4];
            #pragma unroll
            for (int k = 0; k < 4; ++k) mv[k] = *((const float4*)&s_mid[px0 + k][c]);
            #pragma unroll
            for (int r = 0; r < 2; ++r) {
                float w[4]; ld4w<BF16>(pw, (do0 + r) * C_ + c, w);
                #pragma unroll
                for (int k = 0; k < 4; ++k)
                    acc[r][k] += w[0] * mv[k].x + w[1] * mv[k].y + w[2] * mv[k].z + w[3] * mv[k].w;
            }
        }
        #pragma unroll
        for (int r = 0; r < 2; ++r) {
            float pbv = ld1<BF16>(pb, do0 + r);
            float av[4];
            ld4w<BF16>(anchor, (nn * C_ + do0 + r) * HW_ + p0 + px0, av);
            float res[4];
            #pragma unroll
            for (int k = 0; k < 4; ++k) res[k] = acc[r][k] + pbv + av[k];
            st4w<BF16>(outp, (nn * C_ + do0 + r) * HW_ + p0 + px0, res);
        }
    }
#undef S_CAT
}

template<bool TRANS>
__global__ __launch_bounds__(256, 6) void catgemv_kernel(
    const void* __restrict__ curr, const void* __restrict__ anchor,
    const void* __restrict__ s1, const void* __restrict__ s2,
    const void* __restrict__ s3, const void* __restrict__ pw,
    const void* __restrict__ pb, const void* __restrict__ fw,
    const void* __restrict__ fb, void* __restrict__ outp,
    const float* __restrict__ ws_best, const int* __restrict__ ws_gbase)
{
    __shared__ __align__(16) float s_u[P_ * CATP_];   // 18.7 KB
    __shared__ __align__(16) float s_mid[P_][QP_];    // 6.4 KB
    __shared__ float s_best[P_][HEAD_];
    __shared__ int   s_gbase[P_][HEAD_];
    __shared__ int   s_flag;
    const bool bf = block_detect_bf16((const u32*)curr, threadIdx.x, &s_flag);
    if (bf) catgemv_body<true , TRANS>(anchor, s1, s2, s3, pw, pb, fw, fb, outp, ws_best, ws_gbase,
                                       s_u, s_mid, s_best, s_gbase);
    else    catgemv_body<false, TRANS>(anchor, s1, s2, s3, pw, pb, fw, fb, outp, ws_best, ws_gbase,
                                       s_u, s_mid, s_best, s_gbase);
}

// ====================== monolithic fallback (round-2 verbatim, scattered k) ======================
template<bool BF16>
__device__ __forceinline__ void mono_body(
    const void* __restrict__ curr, const void* __restrict__ idxf,
    const void* __restrict__ anchor, const void* __restrict__ s1,
    const void* __restrict__ s2, const void* __restrict__ s3,
    const void* __restrict__ loc, const void* __restrict__ pw,
    const void* __restrict__ pb, const void* __restrict__ fw,
    const void* __restrict__ fb, void* __restrict__ outp,
    float* s_u, float (*s_mid)[QP_], int (*s_lin)[P_], float (*s_red)[8],
    float (*s_best)[HEAD_], int (*s_bidx)[HEAD_], float* s_inv)
{
#define S_Q(pp, ch)  s_u[(pp) * QP_ + (ch)]
#define S_K(pp, ch)  s_u[P_ * QP_ + (pp) * QP_ + (ch)]
#define S_CAT(pp, d) s_u[(pp) * CATP_ + (d)]
    const int tid = threadIdx.x;
    const int b  = blockIdx.x;
    const int nn = b / (HW_ / P_);
    const int p0 = (b - nn * (HW_ / P_)) * P_;

    if (tid < T_ * P_) {
        int t = tid / P_, pp = tid - t * P_;
        int p = p0 + pp;
        float x = ld1<BF16>(loc, (nn * 2 * T_ + 2 * t    ) * HW_ + p);
        float y = ld1<BF16>(loc, (nn * 2 * T_ + 2 * t + 1) * HW_ + p);
        float gx = 2.0f * x / 95.0f - 1.0f;
        float gy = 2.0f * y / 95.0f - 1.0f;
        float fx = (gx + 1.0f) * 0.5f * 95.0f;
        float fy = (gy + 1.0f) * 0.5f * 95.0f;
        float ix = rintf(fx), iy = rintf(fy);
        bool v = (ix >= 0.0f) && (ix <= 95.0f) && (iy >= 0.0f) && (iy <= 95.0f);
        s_lin[t][pp] = v ? ((int)iy * W_ + (int)ix) : -1;
    }
    if (tid >= 128 && tid < 128 + P_ * HEAD_) {
        int q = tid - 128;
        s_best[q >> 2][q & 3] = -3.0e38f; s_bidx[q >> 2][q & 3] = 0;
    }
    for (int i = tid; i < C_ * (P_ / 4); i += 256) {
        int ch = i >> 2, pq = i & 3;
        float w[4];
        ld4w<BF16>(curr, (nn * C_ + ch) * HW_ + p0 + 4 * pq, w);
        S_Q(4 * pq + 0, ch) = w[0]; S_Q(4 * pq + 1, ch) = w[1];
        S_Q(4 * pq + 2, ch) = w[2]; S_Q(4 * pq + 3, ch) = w[3];
    }
    __syncthreads();
    if (tid < P_ * 8) {
        int pp = tid >> 3, j = tid & 7;
        float s = 0.f;
        #pragma unroll
        for (int k = 0; k < 12; ++k) { float v = S_Q(pp, j * 12 + k); s += v * v; }
        s_red[pp][j] = s;
    }
    __syncthreads();
    if (tid < P_) {
        float s = 0.f;
        #pragma unroll
        for (int j = 0; j < 8; ++j) s += s_red[tid][j];
        s_inv[tid] = 1.0f / fmaxf(sqrtf(s), 1e-12f);
    }
    __syncthreads();
    for (int i = tid; i < C_ * P_; i += 256) {
        int pp = i & (P_ - 1), ch = i >> 4;
        S_Q(pp, ch) *= s_inv[pp];
    }
    for (int t = 0; t < T_; ++t) {
        __syncthreads();
        for (int i = tid; i < C_ * P_; i += 256) {
            int ch = i / P_, pp = i - ch * P_;
            int lin = s_lin[t][pp];
            S_K(pp, ch) = (lin >= 0) ? ld1<BF16>(idxf, ((nn * T_ + t) * C_ + ch) * HW_ + lin) : 0.0f;
        }
        __syncthreads();
        if (tid < P_ * 8) {
            int pp = tid >> 3, j = tid & 7;
            float s = 0.f;
            #pragma unroll
            for (int k = 0; k < 12; ++k) { float v = S_K(pp, j * 12 + k); s += v * v; }
            s_red[pp][j] = s;
        }
        __syncthreads();
        if (tid < P_) {
            float s = 0.f;
            #pragma unroll
            for (int j = 0; j < 8; ++j) s += s_red[tid][j];
            s_inv[tid] = 1.0f / fmaxf(sqrtf(s), 1e-12f);
        }
        __syncthreads();
        if (tid < P_ * HEAD_) {
            int pp = tid >> 2, h = tid & 3;
            float s = 0.f;
            #pragma unroll
            for (int dq = 0; dq < 6; ++dq) {
                const float4 kv = *((const float4*)&S_K(pp, h * HD_ + 4 * dq));
                const float4 qv = *((const float4*)&S_Q(pp, h * HD_ + 4 * dq));
                s += kv.x * qv.x; s += kv.y * qv.y; s += kv.z * qv.z; s += kv.w * qv.w;
            }
            s *= s_inv[pp];
            if (s > s_best[pp][h]) { s_best[pp][h] = s; s_bidx[pp][h] = t; }
        }
    }
    __syncthreads();
    for (int i = tid; i < C3_ * P_; i += 256) {
        int pp = i / C3_, d = i - pp * C3_;
        int set = d / C_, ch = d - set * C_;
        int h = ch / HD_;
        int bt = s_bidx[pp][h];
        int lin = s_lin[bt][pp];
        float v = 0.f;
        if (lin >= 0) {
            const void* sp = (set == 0) ? s1 : (set == 1) ? s2 : s3;
            v = ld1<BF16>(sp, ((nn * T_ + bt) * C_ + ch) * HW_ + lin);
        }
        S_CAT(pp, d) = v;
    }
    __syncthreads();
    if (tid < 96) {
        const int cq = tid >> 2, pq = tid & 3;
        const int co0 = cq * 4, px0 = pq * 4;
        float acc[4][4];
        #pragma unroll
        for (int r = 0; r < 4; ++r)
            #pragma unroll
            for (int k = 0; k < 4; ++k) acc[r][k] = 0.f;
        for (int d = 0; d < C3_; d += 4) {
            float4 cv[4];
            #pragma unroll
            for (int k = 0; k < 4; ++k) cv[k] = *((const float4*)&S_CAT(px0 + k, d));
            #pragma unroll
            for (int r = 0; r < 4; ++r) {
                float w[4]; ld4w<BF16>(fw, (co0 + r) * C3_ + d, w);
                #pragma unroll
                for (int k = 0; k < 4; ++k)
                    acc[r][k] += w[0] * cv[k].x + w[1] * cv[k].y + w[2] * cv[k].z + w[3] * cv[k].w;
            }
        }
        const int hh = co0 / HD_;
        #pragma unroll
        for (int r = 0; r < 4; ++r) {
            float fbv = ld1<BF16>(fb, co0 + r);
            #pragma unroll
            for (int k = 0; k < 4; ++k)
                s_mid[px0 + k][co0 + r] = (acc[r][k] + fbv) * s_best[px0 + k][hh];
        }
    }
    __syncthreads();
    if (tid < 96) {
        const int dq = tid >> 2, pq = tid & 3;
        const int do0 = dq * 4, px0 = pq * 4;
        float acc[4][4];
        #pragma unroll
        for (int r = 0; r < 4; ++r)
            #pragma unroll
            for (int k = 0; k < 4; ++k) acc[r][k] = 0.f;
        for (int c = 0; c < C_; c += 4) {
            float4 mv[4];
            #pragma unroll
            for (int k = 0; k < 4; ++k) mv[k] = *((const float4*)&s_mid[px0 + k][c]);
            #pragma unroll
            for (int r = 0; r < 4; ++r) {
                float w[4]; ld4w<BF16>(pw, (do0 + r) * C_ + c, w);
                #pragma unroll
                for (int k = 0; k < 4; ++k)
                    acc[r][k] += w[0] * mv[k].x + w[1] * mv[k].y + w[2] * mv[k].z + w[3] * mv[k].w;
            }
        }
        #pragma unroll
        for (int r = 0; r < 4; ++r) {
            float pbv = ld1<BF16>(pb, do0 + r);
            float av[4];
            ld4w<BF16>(anchor, (nn * C_ + do0 + r) * HW_ + p0 + px0, av);
            float res[4];
            #pragma unroll
            for (int k = 0; k < 4; ++k) res[k] = acc[r][k] + pbv + av[k];
            st4w<BF16>(outp, (nn * C_ + do0 + r) * HW_ + p0 + px0, res);
        }
    }
#undef S_Q
#undef S_K
#undef S_CAT
}

__global__ __launch_bounds__(256) void mono_kernel(
    const void* __restrict__ curr, const void* __restrict__ idxf,
    const void* __restrict__ anchor, const void* __restrict__ s1,
    const void* __restrict__ s2, const void* __restrict__ s3,
    const void* __restrict__ loc, const void* __restrict__ pw,
    const void* __restrict__ pb, const void* __restrict__ fw,
    const void* __restrict__ fb, void* __restrict__ outp)
{
    __shared__ __align__(16) float s_u[P_ * CATP_];
    __shared__ __align__(16) float s_mid[P_][QP_];
    __shared__ int   s_lin[T_][P_];
    __shared__ float s_red[P_][8];
    __shared__ float s_best[P_][HEAD_];
    __shared__ int   s_bidx[P_][HEAD_];
    __shared__ float s_inv[P_];
    __shared__ int   s_flag;
    const bool bf = block_detect_bf16((const u32*)curr, threadIdx.x, &s_flag);
    if (bf) mono_body<true >(curr, idxf, anchor, s1, s2, s3, loc, pw, pb, fw, fb, outp,
                             s_u, s_mid, s_lin, s_red, s_best, s_bidx, s_inv);
    else    mono_body<false>(curr, idxf, anchor, s1, s2, s3, loc, pw, pb, fw, fb, outp,
                             s_u, s_mid, s_lin, s_red, s_best, s_bidx, s_inv);
}

extern "C" void kernel_launch(void* const* d_in, const int* in_sizes, int n_in,
                              void* d_out, int out_size, void* d_ws, size_t ws_size,
                              hipStream_t stream) {
    (void)in_sizes; (void)n_in; (void)out_size;
    const unsigned long long SZB  = (unsigned long long)N_ * T_ * HW_ * C_ * 4ull; // 49,545,216 (f32 worst case)
    const unsigned long long AUXB = (unsigned long long)N_ * HW_ * HEAD_ * 4ull;   // 294,912 B each
    char* wsb = (char*)d_ws;

    dim3 grid(NBLK_), block(256);
    if (ws_size >= 4 * SZB + 2 * AUXB) {
        // FULL mode: transpose idxf + s1/s2/s3; coalesced cat gather
        void*  kT       = wsb;
        void*  s1T      = wsb + SZB;
        void*  s2T      = wsb + 2 * SZB;
        void*  s3T      = wsb + 3 * SZB;
        float* ws_best  = (float*)(wsb + 4 * SZB);
        int*   ws_gbase = (int*)  (wsb + 4 * SZB + AUXB);
        transp_kernel<<<dim3(PLANES_ * NCHUNK_, 4), 256, 0, stream>>>(
            d_in[1], d_in[3], d_in[4], d_in[5], wsb, SZB, (const u32*)d_in[0]);
        argmax_kernel<true><<<grid, block, 0, stream>>>(d_in[0], d_in[6], kT, ws_best, ws_gbase);
        catgemv_kernel<true><<<grid, block, 0, stream>>>(d_in[0], d_in[2], s1T, s2T, s3T,
                                                         d_in[7], d_in[8], d_in[9], d_in[10],
                                                         d_out, ws_best, ws_gbase);
    } else if (ws_size >= SZB + 2 * AUXB) {
        // kT-only mode (round-6 path)
        void*  kT       = wsb;
        float* ws_best  = (float*)(wsb + SZB);
        int*   ws_gbase = (int*)  (wsb + SZB + AUXB);
        transp_kernel<<<dim3(PLANES_ * NCHUNK_, 1), 256, 0, stream>>>(
            d_in[1], d_in[1], d_in[1], d_in[1], wsb, SZB, (const u32*)d_in[0]);
        argmax_kernel<false><<<grid, block, 0, stream>>>(d_in[0], d_in[6], kT, ws_best, ws_gbase);
        catgemv_kernel<false><<<grid, block, 0, stream>>>(d_in[0], d_in[2], d_in[3], d_in[4], d_in[5],
                                                          d_in[7], d_in[8], d_in[9], d_in[10],
                                                          d_out, ws_best, ws_gbase);
    } else {
        mono_kernel<<<grid, block, 0, stream>>>(d_in[0], d_in[1], d_in[2], d_in[3], d_in[4],
                                                d_in[5], d_in[6], d_in[7], d_in[8], d_in[9],
                                                d_in[10], d_out);
    }
}

// Round 8
// 302.520 us; speedup vs baseline: 1.3175x; 1.0312x over previous
//
#include <hip/hip_runtime.h>
#include <hip/hip_bf16.h>

#define N_    2
#define T_    7
#define C_    96
#define H_    96
#define W_    96
#define HW_   9216
#define HEAD_ 4
#define HD_   24
#define C3_   288
#define P_    16           // pixels per block: grid 1152, 256 threads
#define QP_   100          // padded row stride for q/k tiles (mult of 4 -> 16B-aligned)
#define CATP_ 292          // padded row stride for cat tile (mult of 4)
#define NBLK_ (N_ * (HW_ / P_))   // 1152
#define PLANES_ 14         // n*t
#define CHUNK_  64
#define NCHUNK_ 144        // 9216/64
#define TBLK_ (PLANES_ * NCHUNK_) // 2016 transpose blocks per array

typedef unsigned int u32;

__device__ __forceinline__ float bits2f(u32 b) {
    union { u32 u; float f; } x; x.u = b; return x.f;
}

__device__ __forceinline__ unsigned short f2bf(float f) {
    union { __hip_bfloat16 h; unsigned short s; } u;
    u.h = __float2bfloat16(f);
    return u.s;
}

template<bool BF16>
__device__ __forceinline__ float ld1(const void* p, int i) {
    if constexpr (BF16) return bits2f(((u32)((const unsigned short*)p)[i]) << 16);
    else                return ((const float*)p)[i];
}

// load 4 consecutive elements starting at i (i % 4 == 0)
template<bool BF16>
__device__ __forceinline__ void ld4w(const void* p, int i, float w[4]) {
    if constexpr (BF16) {
        const uint2 u = ((const uint2*)p)[i >> 2];
        w[0] = bits2f(u.x << 16);
        w[1] = bits2f(u.x & 0xFFFF0000u);
        w[2] = bits2f(u.y << 16);
        w[3] = bits2f(u.y & 0xFFFF0000u);
    } else {
        const float4 v = *((const float4*)((const float*)p + i));
        w[0] = v.x; w[1] = v.y; w[2] = v.z; w[3] = v.w;
    }
}

template<bool BF16>
__device__ __forceinline__ void st1(void* p, int i, float v) {
    if constexpr (BF16) ((unsigned short*)p)[i] = f2bf(v);
    else                ((float*)p)[i] = v;
}

// store 4 consecutive elements starting at i (i % 4 == 0)
template<bool BF16>
__device__ __forceinline__ void st4w(void* p, int i, const float v[4]) {
    if constexpr (BF16) {
        uint2 w;
        w.x = (u32)f2bf(v[0]) | ((u32)f2bf(v[1]) << 16);
        w.y = (u32)f2bf(v[2]) | ((u32)f2bf(v[3]) << 16);
        ((uint2*)p)[i >> 2] = w;
    } else {
        *((float4*)((float*)p + i)) = make_float4(v[0], v[1], v[2], v[3]);
    }
}

// ---- per-block dtype detect: deterministic, same rule everywhere ----
__device__ __forceinline__ bool block_detect_bf16(const u32* __restrict__ w,
                                                  int tid, int* s_flag) {
    if (tid < 64) {
        u32 x = w[tid];
        u32 f = x & 0x7FFFu;
        int inwin = (f >= 0x3A00u) && (f <= 0x4200u);
        unsigned long long m = __ballot(inwin);
        if (tid == 0) *s_flag = (__popcll(m) >= 40) ? 1 : 0;
    }
    __syncthreads();
    return *s_flag != 0;
}

// ---- (c,hw) -> (hw,c) transpose chunk, bit-exact copy, XOR-swizzled LDS ----
// Tile stored pixel-major [64][96] with col-group swizzle g = chg ^ ((row>>2)&7):
//  - write phase (scalar): 2-way bank aliasing (free)
//  - read phase (b128): aggregate-uniform banks (minimum cycles)
template<bool BF16>
__device__ __forceinline__ void transp_swz(const void* __restrict__ src,
                                           void* __restrict__ dst,
                                           int pl, int x0, int tid, char* raw) {
    if constexpr (BF16) {
        unsigned short* tile = (unsigned short*)raw;      // [64][96] swizzled
        const unsigned short* s = (const unsigned short*)src;
        unsigned short* d = (unsigned short*)dst;
        for (int i = tid; i < C_ * (CHUNK_ / 4); i += 256) {   // 1536
            int ch = i >> 4, xq = i & 15;
            const ushort4 v = *((const ushort4*)(s + (pl * C_ + ch) * HW_ + x0 + 4 * xq));
            int g = (ch >> 2) ^ (xq & 7);                  // (row>>2)&7 == xq&7 for rows 4xq+k
            int chl = ch & 3;
            tile[(4 * xq + 0) * 96 + 4 * g + chl] = v.x;
            tile[(4 * xq + 1) * 96 + 4 * g + chl] = v.y;
            tile[(4 * xq + 2) * 96 + 4 * g + chl] = v.z;
            tile[(4 * xq + 3) * 96 + 4 * g + chl] = v.w;
        }
        __syncthreads();
        for (int i = tid; i < CHUNK_ * (C_ / 4); i += 256) {   // 1536
            int p = i / 24, cq = i - p * 24;
            int g = cq ^ ((p >> 2) & 7);
            const ushort4 v = *((const ushort4*)&tile[p * 96 + 4 * g]);
            *((ushort4*)(d + (pl * HW_ + x0 + p) * C_ + 4 * cq)) = v;
        }
    } else {
        float* tile = (float*)raw;                         // [64][96] swizzled, 24.6 KB
        const float* s = (const float*)src;
        float* d = (float*)dst;
        for (int i = tid; i < C_ * (CHUNK_ / 4); i += 256) {
            int ch = i >> 4, xq = i & 15;
            const float4 v = *((const float4*)(s + (pl * C_ + ch) * HW_ + x0 + 4 * xq));
            int g = (ch >> 2) ^ (xq & 7);
            int chl = ch & 3;
            tile[(4 * xq + 0) * 96 + 4 * g + chl] = v.x;
            tile[(4 * xq + 1) * 96 + 4 * g + chl] = v.y;
            tile[(4 * xq + 2) * 96 + 4 * g + chl] = v.z;
            tile[(4 * xq + 3) * 96 + 4 * g + chl] = v.w;
        }
        __syncthreads();
        for (int i = tid; i < CHUNK_ * (C_ / 4); i += 256) {
            int p = i / 24, cq = i - p * 24;
            int g = cq ^ ((p >> 2) & 7);
            const float4 v = *((const float4*)&tile[p * 96 + 4 * g]);
            *((float4*)(d + (pl * HW_ + x0 + p) * C_ + 4 * cq)) = v;
        }
    }
}

__global__ __launch_bounds__(256) void transp_kernel(
    const void* __restrict__ a0, const void* __restrict__ a1,
    const void* __restrict__ a2, const void* __restrict__ a3,
    void* __restrict__ dstb, unsigned long long szb,
    const u32* __restrict__ detect_src)
{
    __shared__ __align__(16) char raw[24832];
    __shared__ int s_flag;
    const int arr = blockIdx.y;
    const void* src = (arr == 0) ? a0 : (arr == 1) ? a1 : (arr == 2) ? a2 : a3;
    void* dst = (char*)dstb + (unsigned long long)arr * szb;
    const int tid = threadIdx.x;
    const int pl = blockIdx.x / NCHUNK_;
    const int x0 = (blockIdx.x - pl * NCHUNK_) * CHUNK_;
    const bool bf = block_detect_bf16(detect_src, tid, &s_flag);
    if (bf) transp_swz<true >(src, dst, pl, x0, tid, raw);
    else    transp_swz<false>(src, dst, pl, x0, tid, raw);
}

// ====================== argmax body (round-7 verbatim) ======================
template<bool BF16, bool TGB>
__device__ __forceinline__ void argmax_body(
    const void* __restrict__ curr, const void* __restrict__ loc,
    const void* __restrict__ kT,
    float* __restrict__ ws_best, int* __restrict__ ws_gbase,
    float* s_u, int (*s_lin)[P_], float (*s_red)[8],
    float (*s_best)[HEAD_], int (*s_bidx)[HEAD_], float* s_inv)
{
#define S_Q(pp, ch)  s_u[(pp) * QP_ + (ch)]
#define S_K(pp, ch)  s_u[P_ * QP_ + (pp) * QP_ + (ch)]
    const int tid = threadIdx.x;
    const int b  = blockIdx.x;
    const int nn = b / (HW_ / P_);
    const int p0 = (b - nn * (HW_ / P_)) * P_;

    if (tid < T_ * P_) {
        int t = tid / P_, pp = tid - t * P_;
        int p = p0 + pp;
        float x = ld1<BF16>(loc, (nn * 2 * T_ + 2 * t    ) * HW_ + p);
        float y = ld1<BF16>(loc, (nn * 2 * T_ + 2 * t + 1) * HW_ + p);
        float gx = 2.0f * x / 95.0f - 1.0f;
        float gy = 2.0f * y / 95.0f - 1.0f;
        float fx = (gx + 1.0f) * 0.5f * 95.0f;
        float fy = (gy + 1.0f) * 0.5f * 95.0f;
        float ix = rintf(fx), iy = rintf(fy);     // round-half-even == jnp.round
        bool v = (ix >= 0.0f) && (ix <= 95.0f) && (iy >= 0.0f) && (iy <= 95.0f);
        s_lin[t][pp] = v ? ((int)iy * W_ + (int)ix) : -1;
    }
    if (tid >= 128 && tid < 128 + P_ * HEAD_) {
        int q = tid - 128;
        s_best[q >> 2][q & 3] = -3.0e38f; s_bidx[q >> 2][q & 3] = 0;
    }

    for (int i = tid; i < C_ * (P_ / 4); i += 256) {
        int ch = i >> 2, pq = i & 3;
        float w[4];
        ld4w<BF16>(curr, (nn * C_ + ch) * HW_ + p0 + 4 * pq, w);
        S_Q(4 * pq + 0, ch) = w[0]; S_Q(4 * pq + 1, ch) = w[1];
        S_Q(4 * pq + 2, ch) = w[2]; S_Q(4 * pq + 3, ch) = w[3];
    }
    __syncthreads();

    if (tid < P_ * 8) {
        int pp = tid >> 3, j = tid & 7;
        float s = 0.f;
        #pragma unroll
        for (int k = 0; k < 12; ++k) { float v = S_Q(pp, j * 12 + k); s += v * v; }
        s_red[pp][j] = s;
    }
    __syncthreads();
    if (tid < P_) {
        float s = 0.f;
        #pragma unroll
        for (int j = 0; j < 8; ++j) s += s_red[tid][j];
        s_inv[tid] = 1.0f / fmaxf(sqrtf(s), 1e-12f);
    }
    __syncthreads();
    for (int i = tid; i < C_ * P_; i += 256) {
        int pp = i & (P_ - 1), ch = i >> 4;
        S_Q(pp, ch) *= s_inv[pp];
    }

    for (int t = 0; t < T_; ++t) {
        __syncthreads();
        for (int i = tid; i < 24 * P_; i += 256) {
            int pp = i / 24, j = i - pp * 24;
            int lin = s_lin[t][pp];
            float w[4] = {0.f, 0.f, 0.f, 0.f};
            if (lin >= 0) ld4w<BF16>(kT, ((nn * T_ + t) * HW_ + lin) * C_ + 4 * j, w);
            *((float4*)&S_K(pp, 4 * j)) = make_float4(w[0], w[1], w[2], w[3]);
        }
        __syncthreads();
        if (tid < P_ * 8) {
            int pp = tid >> 3, j = tid & 7;
            float s = 0.f;
            #pragma unroll
            for (int k = 0; k < 12; ++k) { float v = S_K(pp, j * 12 + k); s += v * v; }
            s_red[pp][j] = s;
        }
        __syncthreads();
        if (tid < P_) {
            float s = 0.f;
            #pragma unroll
            for (int j = 0; j < 8; ++j) s += s_red[tid][j];
            s_inv[tid] = 1.0f / fmaxf(sqrtf(s), 1e-12f);
        }
        __syncthreads();
        if (tid < P_ * HEAD_) {
            int pp = tid >> 2, h = tid & 3;
            float s = 0.f;
            #pragma unroll
            for (int dq = 0; dq < 6; ++dq) {
                const float4 kv = *((const float4*)&S_K(pp, h * HD_ + 4 * dq));
                const float4 qv = *((const float4*)&S_Q(pp, h * HD_ + 4 * dq));
                s += kv.x * qv.x; s += kv.y * qv.y; s += kv.z * qv.z; s += kv.w * qv.w;
            }
            s *= s_inv[pp];
            if (s > s_best[pp][h]) { s_best[pp][h] = s; s_bidx[pp][h] = t; }  // strict > == first-max
        }
    }
    if (tid < P_ * HEAD_) {
        int pp = tid >> 2, h = tid & 3;
        int bt = s_bidx[pp][h];
        int lin = s_lin[bt][pp];
        int g = (nn * HW_ + p0 + pp) * HEAD_ + h;
        ws_best[g] = s_best[pp][h];
        int gb;
        if (lin < 0)       gb = -1;
        else if (TGB)      gb = ((nn * T_ + bt) * HW_ + lin) * C_;   // transposed (hw,c) coords
        else               gb = (nn * T_ + bt) * C_ * HW_ + lin;     // original (c,hw) coords
        ws_gbase[g] = gb;
    }
#undef S_Q
#undef S_K
}

// standalone argmax (kT-only fallback mode)
template<bool TGB>
__global__ __launch_bounds__(256, 8) void argmax_kernel(
    const void* __restrict__ curr, const void* __restrict__ loc,
    const void* __restrict__ kT,
    float* __restrict__ ws_best, int* __restrict__ ws_gbase)
{
    __shared__ __align__(16) float s_u[2 * P_ * QP_];   // q | k  (12.8 KB)
    __shared__ int   s_lin[T_][P_];
    __shared__ float s_red[P_][8];
    __shared__ float s_best[P_][HEAD_];
    __shared__ int   s_bidx[P_][HEAD_];
    __shared__ float s_inv[P_];
    __shared__ int   s_flag;
    const bool bf = block_detect_bf16((const u32*)curr, threadIdx.x, &s_flag);
    if (bf) argmax_body<true , TGB>(curr, loc, kT, ws_best, ws_gbase, s_u, s_lin, s_red, s_best, s_bidx, s_inv);
    else    argmax_body<false, TGB>(curr, loc, kT, ws_best, ws_gbase, s_u, s_lin, s_red, s_best, s_bidx, s_inv);
}

// ====================== FUSED: argmax blocks + s1/s2/s3-transpose blocks ======================
// bx < NBLK_: argmax (all 1152 co-resident, latency-bound).
// bx >= NBLK_: transpose chunks of s1/s2/s3 (BW-bound) — overlaps with argmax.
__global__ __launch_bounds__(256, 6) void fused_kernel(
    const void* __restrict__ curr, const void* __restrict__ loc,
    const void* __restrict__ kT,
    const void* __restrict__ s1, const void* __restrict__ s2,
    const void* __restrict__ s3,
    void* __restrict__ s123T, unsigned long long szb,
    float* __restrict__ ws_best, int* __restrict__ ws_gbase)
{
    __shared__ __align__(16) char raw[24832];   // transp tile (24.6 KB) / argmax arrays overlay
    __shared__ int s_flag;
    const int tid = threadIdx.x;
    const bool bf = block_detect_bf16((const u32*)curr, tid, &s_flag);
    const int bx = blockIdx.x;
    if (bx < NBLK_) {
        float* s_u            = (float*)raw;                        // 12800 B
        int   (*s_lin)[P_]    = (int(*)[P_])   (raw + 12800);       // 448
        float (*s_red)[8]     = (float(*)[8])  (raw + 13248);       // 512
        float (*s_best)[HEAD_]= (float(*)[HEAD_])(raw + 13760);     // 256
        int   (*s_bidx)[HEAD_]= (int(*)[HEAD_]) (raw + 14016);      // 256
        float* s_inv          = (float*)(raw + 14272);              // 64
        if (bf) argmax_body<true , true>(curr, loc, kT, ws_best, ws_gbase,
                                         s_u, s_lin, s_red, s_best, s_bidx, s_inv);
        else    argmax_body<false, true>(curr, loc, kT, ws_best, ws_gbase,
                                         s_u, s_lin, s_red, s_best, s_bidx, s_inv);
    } else {
        int t = bx - NBLK_;
        int arr = t / TBLK_;
        int bxx = t - arr * TBLK_;
        const void* src = (arr == 0) ? s1 : (arr == 1) ? s2 : s3;
        void* dst = (char*)s123T + (unsigned long long)arr * szb;
        int pl = bxx / NCHUNK_;
        int x0 = (bxx - pl * NCHUNK_) * CHUNK_;
        if (bf) transp_swz<true >(src, dst, pl, x0, tid, raw);
        else    transp_swz<false>(src, dst, pl, x0, tid, raw);
    }
}

// ====================== KERNEL B: cat gather + GEMVs (round-7 verbatim) ======================
template<bool BF16, bool TRANS>
__device__ __forceinline__ void catgemv_body(
    const void* __restrict__ anchor, const void* __restrict__ s1,
    const void* __restrict__ s2, const void* __restrict__ s3,
    const void* __restrict__ pw, const void* __restrict__ pb,
    const void* __restrict__ fw, const void* __restrict__ fb,
    void* __restrict__ outp,
    const float* __restrict__ ws_best, const int* __restrict__ ws_gbase,
    float* s_u, float (*s_mid)[QP_], float (*s_best)[HEAD_], int (*s_gbase)[HEAD_])
{
#define S_CAT(pp, d) s_u[(pp) * CATP_ + (d)]
    const int tid = threadIdx.x;
    const int b  = blockIdx.x;
    const int nn = b / (HW_ / P_);
    const int p0 = (b - nn * (HW_ / P_)) * P_;

    if (tid < P_ * HEAD_) {
        int pp = tid >> 2, h = tid & 3;
        int g = (nn * HW_ + p0 + pp) * HEAD_ + h;
        s_best[pp][h]  = ws_best[g];
        s_gbase[pp][h] = ws_gbase[g];
    }
    __syncthreads();

    if constexpr (TRANS) {
        for (int i = tid; i < P_ * 72; i += 256) {
            int px = i / 72, j = i - px * 72;
            int set = j / 24, jj = j - set * 24;        // ch = 4*jj
            int gb = s_gbase[px][jj / 6];               // head = (4*jj)/24
            float w[4] = {0.f, 0.f, 0.f, 0.f};
            if (gb >= 0) {
                const void* sp = (set == 0) ? s1 : (set == 1) ? s2 : s3;
                ld4w<BF16>(sp, gb + 4 * jj, w);
            }
            *((float4*)&S_CAT(px, set * C_ + 4 * jj)) = make_float4(w[0], w[1], w[2], w[3]);
        }
    } else {
        for (int i = tid; i < C3_ * P_; i += 256) {
            int pp = i / C3_, d = i - pp * C3_;
            int set = d / C_, ch = d - set * C_;
            int gb = s_gbase[pp][ch / HD_];
            float v = 0.f;
            if (gb >= 0) {
                const void* sp = (set == 0) ? s1 : (set == 1) ? s2 : s3;
                v = ld1<BF16>(sp, gb + ch * HW_);
            }
            S_CAT(pp, d) = v;
        }
    }
    __syncthreads();

    if (tid < 192) {
        const int cp = tid >> 2, pq = tid & 3;
        const int co0 = cp * 2, px0 = pq * 4;
        float acc[2][4];
        #pragma unroll
        for (int r = 0; r < 2; ++r)
            #pragma unroll
            for (int k = 0; k < 4; ++k) acc[r][k] = 0.f;
        for (int d = 0; d < C3_; d += 4) {
            float4 cv[4];
            #pragma unroll
            for (int k = 0; k < 4; ++k) cv[k] = *((const float4*)&S_CAT(px0 + k, d));
            #pragma unroll
            for (int r = 0; r < 2; ++r) {
                float w[4]; ld4w<BF16>(fw, (co0 + r) * C3_ + d, w);
                #pragma unroll
                for (int k = 0; k < 4; ++k)
                    acc[r][k] += w[0] * cv[k].x + w[1] * cv[k].y + w[2] * cv[k].z + w[3] * cv[k].w;
            }
        }
        const int hh = co0 / HD_;
        #pragma unroll
        for (int r = 0; r < 2; ++r) {
            float fbv = ld1<BF16>(fb, co0 + r);
            #pragma unroll
            for (int k = 0; k < 4; ++k)
                s_mid[px0 + k][co0 + r] = (acc[r][k] + fbv) * s_best[px0 + k][hh];
        }
    }
    __syncthreads();

    if (tid < 192) {
        const int dp = tid >> 2, pq = tid & 3;
        const int do0 = dp * 2, px0 = pq * 4;
        float acc[2][4];
        #pragma unroll
        for (int r = 0; r < 2; ++r)
            #pragma unroll
            for (int k = 0; k < 4; ++k) acc[r][k] = 0.f;
        for (int c = 0; c < C_; c += 4) {
            float4 mv[4];
            #pragma unroll
            for (int k = 0; k < 4; ++k) mv[k] = *((const float4*)&s_mid[px0 + k][c]);
            #pragma unroll
            for (int r = 0; r < 2; ++r) {
                float w[4]; ld4w<BF16>(pw, (do0 + r) * C_ + c, w);
                #pragma unroll
                for (int k = 0; k < 4; ++k)
                    acc[r][k] += w[0] * mv[k].x + w[1] * mv[k].y + w[2] * mv[k].z + w[3] * mv[k].w;
            }
        }
        #pragma unroll
        for (int r = 0; r < 2; ++r) {
            float pbv = ld1<BF16>(pb, do0 + r);
            float av[4];
            ld4w<BF16>(anchor, (nn * C_ + do0 + r) * HW_ + p0 + px0, av);
            float res[4];
            #pragma unroll
            for (int k = 0; k < 4; ++k) res[k] = acc[r][k] + pbv + av[k];
            st4w<BF16>(outp, (nn * C_ + do0 + r) * HW_ + p0 + px0, res);
        }
    }
#undef S_CAT
}

template<bool TRANS>
__global__ __launch_bounds__(256, 6) void catgemv_kernel(
    const void* __restrict__ curr, const void* __restrict__ anchor,
    const void* __restrict__ s1, const void* __restrict__ s2,
    const void* __restrict__ s3, const void* __restrict__ pw,
    const void* __restrict__ pb, const void* __restrict__ fw,
    const void* __restrict__ fb, void* __restrict__ outp,
    const float* __restrict__ ws_best, const int* __restrict__ ws_gbase)
{
    __shared__ __align__(16) float s_u[P_ * CATP_];   // 18.7 KB
    __shared__ __align__(16) float s_mid[P_][QP_];    // 6.4 KB
    __shared__ float s_best[P_][HEAD_];
    __shared__ int   s_gbase[P_][HEAD_];
    __shared__ int   s_flag;
    const bool bf = block_detect_bf16((const u32*)curr, threadIdx.x, &s_flag);
    if (bf) catgemv_body<true , TRANS>(anchor, s1, s2, s3, pw, pb, fw, fb, outp, ws_best, ws_gbase,
                                       s_u, s_mid, s_best, s_gbase);
    else    catgemv_body<false, TRANS>(anchor, s1, s2, s3, pw, pb, fw, fb, outp, ws_best, ws_gbase,
                                       s_u, s_mid, s_best, s_gbase);
}

// ====================== monolithic fallback (round-2 verbatim, scattered k) ======================
template<bool BF16>
__device__ __forceinline__ void mono_body(
    const void* __restrict__ curr, const void* __restrict__ idxf,
    const void* __restrict__ anchor, const void* __restrict__ s1,
    const void* __restrict__ s2, const void* __restrict__ s3,
    const void* __restrict__ loc, const void* __restrict__ pw,
    const void* __restrict__ pb, const void* __restrict__ fw,
    const void* __restrict__ fb, void* __restrict__ outp,
    float* s_u, float (*s_mid)[QP_], int (*s_lin)[P_], float (*s_red)[8],
    float (*s_best)[HEAD_], int (*s_bidx)[HEAD_], float* s_inv)
{
#define S_Q(pp, ch)  s_u[(pp) * QP_ + (ch)]
#define S_K(pp, ch)  s_u[P_ * QP_ + (pp) * QP_ + (ch)]
#define S_CAT(pp, d) s_u[(pp) * CATP_ + (d)]
    const int tid = threadIdx.x;
    const int b  = blockIdx.x;
    const int nn = b / (HW_ / P_);
    const int p0 = (b - nn * (HW_ / P_)) * P_;

    if (tid < T_ * P_) {
        int t = tid / P_, pp = tid - t * P_;
        int p = p0 + pp;
        float x = ld1<BF16>(loc, (nn * 2 * T_ + 2 * t    ) * HW_ + p);
        float y = ld1<BF16>(loc, (nn * 2 * T_ + 2 * t + 1) * HW_ + p);
        float gx = 2.0f * x / 95.0f - 1.0f;
        float gy = 2.0f * y / 95.0f - 1.0f;
        float fx = (gx + 1.0f) * 0.5f * 95.0f;
        float fy = (gy + 1.0f) * 0.5f * 95.0f;
        float ix = rintf(fx), iy = rintf(fy);
        bool v = (ix >= 0.0f) && (ix <= 95.0f) && (iy >= 0.0f) && (iy <= 95.0f);
        s_lin[t][pp] = v ? ((int)iy * W_ + (int)ix) : -1;
    }
    if (tid >= 128 && tid < 128 + P_ * HEAD_) {
        int q = tid - 128;
        s_best[q >> 2][q & 3] = -3.0e38f; s_bidx[q >> 2][q & 3] = 0;
    }
    for (int i = tid; i < C_ * (P_ / 4); i += 256) {
        int ch = i >> 2, pq = i & 3;
        float w[4];
        ld4w<BF16>(curr, (nn * C_ + ch) * HW_ + p0 + 4 * pq, w);
        S_Q(4 * pq + 0, ch) = w[0]; S_Q(4 * pq + 1, ch) = w[1];
        S_Q(4 * pq + 2, ch) = w[2]; S_Q(4 * pq + 3, ch) = w[3];
    }
    __syncthreads();
    if (tid < P_ * 8) {
        int pp = tid >> 3, j = tid & 7;
        float s = 0.f;
        #pragma unroll
        for (int k = 0; k < 12; ++k) { float v = S_Q(pp, j * 12 + k); s += v * v; }
        s_red[pp][j] = s;
    }
    __syncthreads();
    if (tid < P_) {
        float s = 0.f;
        #pragma unroll
        for (int j = 0; j < 8; ++j) s += s_red[tid][j];
        s_inv[tid] = 1.0f / fmaxf(sqrtf(s), 1e-12f);
    }
    __syncthreads();
    for (int i = tid; i < C_ * P_; i += 256) {
        int pp = i & (P_ - 1), ch = i >> 4;
        S_Q(pp, ch) *= s_inv[pp];
    }
    for (int t = 0; t < T_; ++t) {
        __syncthreads();
        for (int i = tid; i < C_ * P_; i += 256) {
            int ch = i / P_, pp = i - ch * P_;
            int lin = s_lin[t][pp];
            S_K(pp, ch) = (lin >= 0) ? ld1<BF16>(idxf, ((nn * T_ + t) * C_ + ch) * HW_ + lin) : 0.0f;
        }
        __syncthreads();
        if (tid < P_ * 8) {
            int pp = tid >> 3, j = tid & 7;
            float s = 0.f;
            #pragma unroll
            for (int k = 0; k < 12; ++k) { float v = S_K(pp, j * 12 + k); s += v * v; }
            s_red[pp][j] = s;
        }
        __syncthreads();
        if (tid < P_) {
            float s = 0.f;
            #pragma unroll
            for (int j = 0; j < 8; ++j) s += s_red[tid][j];
            s_inv[tid] = 1.0f / fmaxf(sqrtf(s), 1e-12f);
        }
        __syncthreads();
        if (tid < P_ * HEAD_) {
            int pp = tid >> 2, h = tid & 3;
            float s = 0.f;
            #pragma unroll
            for (int dq = 0; dq < 6; ++dq) {
                const float4 kv = *((const float4*)&S_K(pp, h * HD_ + 4 * dq));
                const float4 qv = *((const float4*)&S_Q(pp, h * HD_ + 4 * dq));
                s += kv.x * qv.x; s += kv.y * qv.y; s += kv.z * qv.z; s += kv.w * qv.w;
            }
            s *= s_inv[pp];
            if (s > s_best[pp][h]) { s_best[pp][h] = s; s_bidx[pp][h] = t; }
        }
    }
    __syncthreads();
    for (int i = tid; i < C3_ * P_; i += 256) {
        int pp = i / C3_, d = i - pp * C3_;
        int set = d / C_, ch = d - set * C_;
        int h = ch / HD_;
        int bt = s_bidx[pp][h];
        int lin = s_lin[bt][pp];
        float v = 0.f;
        if (lin >= 0) {
            const void* sp = (set == 0) ? s1 : (set == 1) ? s2 : s3;
            v = ld1<BF16>(sp, ((nn * T_ + bt) * C_ + ch) * HW_ + lin);
        }
        S_CAT(pp, d) = v;
    }
    __syncthreads();
    if (tid < 96) {
        const int cq = tid >> 2, pq = tid & 3;
        const int co0 = cq * 4, px0 = pq * 4;
        float acc[4][4];
        #pragma unroll
        for (int r = 0; r < 4; ++r)
            #pragma unroll
            for (int k = 0; k < 4; ++k) acc[r][k] = 0.f;
        for (int d = 0; d < C3_; d += 4) {
            float4 cv[4];
            #pragma unroll
            for (int k = 0; k < 4; ++k) cv[k] = *((const float4*)&S_CAT(px0 + k, d));
            #pragma unroll
            for (int r = 0; r < 4; ++r) {
                float w[4]; ld4w<BF16>(fw, (co0 + r) * C3_ + d, w);
                #pragma unroll
                for (int k = 0; k < 4; ++k)
                    acc[r][k] += w[0] * cv[k].x + w[1] * cv[k].y + w[2] * cv[k].z + w[3] * cv[k].w;
            }
        }
        const int hh = co0 / HD_;
        #pragma unroll
        for (int r = 0; r < 4; ++r) {
            float fbv = ld1<BF16>(fb, co0 + r);
            #pragma unroll
            for (int k = 0; k < 4; ++k)
                s_mid[px0 + k][co0 + r] = (acc[r][k] + fbv) * s_best[px0 + k][hh];
        }
    }
    __syncthreads();
    if (tid < 96) {
        const int dq = tid >> 2, pq = tid & 3;
        const int do0 = dq * 4, px0 = pq * 4;
        float acc[4][4];
        #pragma unroll
        for (int r = 0; r < 4; ++r)
            #pragma unroll
            for (int k = 0; k < 4; ++k) acc[r][k] = 0.f;
        for (int c = 0; c < C_; c += 4) {
            float4 mv[4];
            #pragma unroll
            for (int k = 0; k < 4; ++k) mv[k] = *((const float4*)&s_mid[px0 + k][c]);
            #pragma unroll
            for (int r = 0; r < 4; ++r) {
                float w[4]; ld4w<BF16>(pw, (do0 + r) * C_ + c, w);
                #pragma unroll
                for (int k = 0; k < 4; ++k)
                    acc[r][k] += w[0] * mv[k].x + w[1] * mv[k].y + w[2] * mv[k].z + w[3] * mv[k].w;
            }
        }
        #pragma unroll
        for (int r = 0; r < 4; ++r) {
            float pbv = ld1<BF16>(pb, do0 + r);
            float av[4];
            ld4w<BF16>(anchor, (nn * C_ + do0 + r) * HW_ + p0 + px0, av);
            float res[4];
            #pragma unroll
            for (int k = 0; k < 4; ++k) res[k] = acc[r][k] + pbv + av[k];
            st4w<BF16>(outp, (nn * C_ + do0 + r) * HW_ + p0 + px0, res);
        }
    }
#undef S_Q
#undef S_K
#undef S_CAT
}

__global__ __launch_bounds__(256) void mono_kernel(
    const void* __restrict__ curr, const void* __restrict__ idxf,
    const void* __restrict__ anchor, const void* __restrict__ s1,
    const void* __restrict__ s2, const void* __restrict__ s3,
    const void* __restrict__ loc, const void* __restrict__ pw,
    const void* __restrict__ pb, const void* __restrict__ fw,
    const void* __restrict__ fb, void* __restrict__ outp)
{
    __shared__ __align__(16) float s_u[P_ * CATP_];
    __shared__ __align__(16) float s_mid[P_][QP_];
    __shared__ int   s_lin[T_][P_];
    __shared__ float s_red[P_][8];
    __shared__ float s_best[P_][HEAD_];
    __shared__ int   s_bidx[P_][HEAD_];
    __shared__ float s_inv[P_];
    __shared__ int   s_flag;
    const bool bf = block_detect_bf16((const u32*)curr, threadIdx.x, &s_flag);
    if (bf) mono_body<true >(curr, idxf, anchor, s1, s2, s3, loc, pw, pb, fw, fb, outp,
                             s_u, s_mid, s_lin, s_red, s_best, s_bidx, s_inv);
    else    mono_body<false>(curr, idxf, anchor, s1, s2, s3, loc, pw, pb, fw, fb, outp,
                             s_u, s_mid, s_lin, s_red, s_best, s_bidx, s_inv);
}

extern "C" void kernel_launch(void* const* d_in, const int* in_sizes, int n_in,
                              void* d_out, int out_size, void* d_ws, size_t ws_size,
                              hipStream_t stream) {
    (void)in_sizes; (void)n_in; (void)out_size;
    const unsigned long long SZB  = (unsigned long long)N_ * T_ * HW_ * C_ * 4ull; // 49,545,216 (f32 worst case)
    const unsigned long long AUXB = (unsigned long long)N_ * HW_ * HEAD_ * 4ull;   // 294,912 B each
    char* wsb = (char*)d_ws;

    dim3 grid(NBLK_), block(256);
    if (ws_size >= 4 * SZB + 2 * AUXB) {
        // FULL mode: kT transpose -> fused(argmax || s123 transpose) -> catgemv
        void*  kT       = wsb;
        void*  s123T    = wsb + SZB;
        float* ws_best  = (float*)(wsb + 4 * SZB);
        int*   ws_gbase = (int*)  (wsb + 4 * SZB + AUXB);
        transp_kernel<<<dim3(TBLK_, 1), 256, 0, stream>>>(
            d_in[1], d_in[1], d_in[1], d_in[1], kT, SZB, (const u32*)d_in[0]);
        fused_kernel<<<dim3(NBLK_ + 3 * TBLK_), 256, 0, stream>>>(
            d_in[0], d_in[6], kT, d_in[3], d_in[4], d_in[5], s123T, SZB, ws_best, ws_gbase);
        catgemv_kernel<true><<<grid, block, 0, stream>>>(
            d_in[0], d_in[2],
            (char*)s123T, (char*)s123T + SZB, (char*)s123T + 2 * SZB,
            d_in[7], d_in[8], d_in[9], d_in[10], d_out, ws_best, ws_gbase);
    } else if (ws_size >= SZB + 2 * AUXB) {
        // kT-only mode (round-6 path)
        void*  kT       = wsb;
        float* ws_best  = (float*)(wsb + SZB);
        int*   ws_gbase = (int*)  (wsb + SZB + AUXB);
        transp_kernel<<<dim3(TBLK_, 1), 256, 0, stream>>>(
            d_in[1], d_in[1], d_in[1], d_in[1], kT, SZB, (const u32*)d_in[0]);
        argmax_kernel<false><<<grid, block, 0, stream>>>(d_in[0], d_in[6], kT, ws_best, ws_gbase);
        catgemv_kernel<false><<<grid, block, 0, stream>>>(d_in[0], d_in[2], d_in[3], d_in[4], d_in[5],
                                                          d_in[7], d_in[8], d_in[9], d_in[10],
                                                          d_out, ws_best, ws_gbase);
    } else {
        mono_kernel<<<grid, block, 0, stream>>>(d_in[0], d_in[1], d_in[2], d_in[3], d_in[4],
                                                d_in[5], d_in[6], d_in[7], d_in[8], d_in[9],
                                                d_in[10], d_out);
    }
}